// Round 2
// baseline (770.054 us; speedup 1.0000x reference)
//
#include <hip/hip_runtime.h>

// GraphSAGE 2-hop, fp32, CSR-gather aggregation (no float atomics).
//   deg[i]     = #edges with dst==i           (int atomics)
//   row_start  = exclusive scan of deg        (single-block scan)
//   esrc       = edge sources bucketed by dst (int atomics on cursors)
//   agg1       = mean_{e: dst=i} x[src[e]]    (gather, one 32-lane group/node)
//   h          = relu([agg1, x] @ [W1l; W1r] + b1)   (virtual-K fp32 GEMM)
//   agg2       = mean gather of h             (64-lane group/node)
//   out        = [agg2, h] @ [W2l; W2r] + b2

constexpr int HIDC = 256;

__global__ __launch_bounds__(256) void deg_count_kernel(
    const int* __restrict__ dst, int* __restrict__ deg, int E, int N) {
  int e = blockIdx.x * blockDim.x + threadIdx.x;
  if (e < E) {
    int d = dst[e];
    if ((unsigned)d < (unsigned)N) atomicAdd(&deg[d], 1);
  }
}

// Single block, 256 threads: exclusive scan of deg -> row_start[0..N], and
// initialize cursor[i] = row_start[i].
__global__ __launch_bounds__(256) void scan_kernel(
    const int* __restrict__ deg, int* __restrict__ row_start,
    int* __restrict__ cursor, int N) {
  __shared__ int sums[256];
  const int t = threadIdx.x;
  const int chunk = (N + 255) / 256;
  const int lo = t * chunk;
  const int hi = (lo + chunk < N) ? lo + chunk : N;
  int s = 0;
  for (int i = lo; i < hi; ++i) s += deg[i];
  sums[t] = s;
  __syncthreads();
  // Hillis-Steele inclusive scan over the 256 partials.
  for (int off = 1; off < 256; off <<= 1) {
    int v = (t >= off) ? sums[t - off] : 0;
    __syncthreads();
    sums[t] += v;
    __syncthreads();
  }
  int base = (t == 0) ? 0 : sums[t - 1];
  for (int i = lo; i < hi; ++i) {
    row_start[i] = base;
    cursor[i] = base;
    base += deg[i];
  }
  if (t == 255) row_start[N] = sums[255];
}

__global__ __launch_bounds__(256) void fill_kernel(
    const int* __restrict__ src, const int* __restrict__ dst,
    int* __restrict__ cursor, int* __restrict__ esrc, int E, int N) {
  int e = blockIdx.x * blockDim.x + threadIdx.x;
  if (e < E) {
    int d = dst[e];
    if ((unsigned)d < (unsigned)N) {
      int p = atomicAdd(&cursor[d], 1);
      esrc[p] = src[e];
    }
  }
}

// One DQ-lane group per node; lane l owns float4 column-chunk l.
// agg[i] = (1/max(deg,1)) * sum_{e in CSR row i} x[esrc[e]]  (full overwrite)
template <int DQ>
__global__ __launch_bounds__(256) void gather_mean_kernel(
    const float4* __restrict__ xf, const int* __restrict__ row_start,
    const int* __restrict__ esrc, float4* __restrict__ agg, int N) {
  const int gid = (int)(((long long)blockIdx.x * 256 + threadIdx.x) / DQ);
  const int l = threadIdx.x & (DQ - 1);
  if (gid >= N) return;
  const int lo = row_start[gid];
  const int hi = row_start[gid + 1];
  float4 acc = make_float4(0.f, 0.f, 0.f, 0.f);
  int e = lo;
  for (; e + 1 < hi; e += 2) {  // 2-edge unroll for a little ILP
    int s0 = esrc[e];
    int s1 = esrc[e + 1];
    float4 v0 = xf[(size_t)s0 * DQ + l];
    float4 v1 = xf[(size_t)s1 * DQ + l];
    acc.x += v0.x + v1.x;
    acc.y += v0.y + v1.y;
    acc.z += v0.z + v1.z;
    acc.w += v0.w + v1.w;
  }
  if (e < hi) {
    int s0 = esrc[e];
    float4 v0 = xf[(size_t)s0 * DQ + l];
    acc.x += v0.x;
    acc.y += v0.y;
    acc.z += v0.z;
    acc.w += v0.w;
  }
  const float inv = (hi > lo) ? 1.0f / (float)(hi - lo) : 0.0f;
  acc.x *= inv;
  acc.y *= inv;
  acc.z *= inv;
  acc.w *= inv;
  agg[(size_t)gid * DQ + l] = acc;
}

// C[i,j] = (relu?)( sum_k A[i,k] Wl[k,j] + sum_k X[i,k] Wr[k,j] + bias[j] )
// A already mean-normalized. Virtual K = 2*K1 (first half A/Wl, second X/Wr).
// BM=64, BN=128, BK=32; 128 threads, 8x8 per thread (4+4 rows at +32,
// 4+4 cols at +64 so every wave ds_read_b128 is <=2-way bank aliased).
template <int K1, bool RELU>
__global__ __launch_bounds__(128) void sage_gemm(
    const float* __restrict__ A, const float* __restrict__ X,
    const float* __restrict__ Wl, const float* __restrict__ Wr,
    const float* __restrict__ bias, float* __restrict__ C, int nrows) {
  constexpr int BM = 64, BN = 128, BK = 32;
  __shared__ float As[BK][BM + 4];  // transposed: As[k][m]
  __shared__ float Bs[BK][BN + 4];

  const int tid = threadIdx.x;     // 0..127
  const int brow = blockIdx.x * BM;
  const int bcol = blockIdx.y * BN;
  const int rm = (tid >> 4) * 4;   // rows rm..rm+3 and rm+32..rm+35
  const int cn = (tid & 15) * 4;   // cols cn..cn+3 and cn+64..cn+67
  const int ar = tid >> 3;         // A-stage: row within 16-row pass
  const int ac = (tid & 7) * 4;    // A-stage: k chunk (float4)
  const int br = tid >> 5;         // B-stage: k row within 4-row pass
  const int bc = (tid & 31) * 4;   // B-stage: col chunk (float4)

  float acc[8][8];
#pragma unroll
  for (int i = 0; i < 8; ++i)
#pragma unroll
    for (int j = 0; j < 8; ++j) acc[i][j] = 0.f;

  for (int k0 = 0; k0 < 2 * K1; k0 += BK) {
    const bool left = (k0 < K1);
    const int kk = left ? k0 : k0 - K1;
    const float* __restrict__ S = left ? A : X;
    const float* __restrict__ W = left ? Wl : Wr;
    // ---- stage A tile (transposed into LDS), 4 passes of 16 rows ----
#pragma unroll
    for (int p = 0; p < 4; ++p) {
      int m = ar + p * 16;
      int gr = brow + m;
      float4 v = make_float4(0.f, 0.f, 0.f, 0.f);
      if (gr < nrows) v = *(const float4*)(S + (size_t)gr * K1 + kk + ac);
      As[ac + 0][m] = v.x;
      As[ac + 1][m] = v.y;
      As[ac + 2][m] = v.z;
      As[ac + 3][m] = v.w;
    }
    // ---- stage B tile, 8 passes of 4 k-rows ----
#pragma unroll
    for (int p = 0; p < 8; ++p) {
      int r = br + p * 4;
      *(float4*)&Bs[r][bc] = *(const float4*)(W + (size_t)(kk + r) * HIDC + bcol + bc);
    }
    __syncthreads();
    // ---- compute: 8x8 outer product per k ----
#pragma unroll
    for (int k = 0; k < BK; ++k) {
      float4 a0 = *(const float4*)&As[k][rm];
      float4 a1 = *(const float4*)&As[k][rm + 32];
      float4 b0 = *(const float4*)&Bs[k][cn];
      float4 b1 = *(const float4*)&Bs[k][cn + 64];
      float av[8] = {a0.x, a0.y, a0.z, a0.w, a1.x, a1.y, a1.z, a1.w};
      float bv[8] = {b0.x, b0.y, b0.z, b0.w, b1.x, b1.y, b1.z, b1.w};
#pragma unroll
      for (int i = 0; i < 8; ++i)
#pragma unroll
        for (int j = 0; j < 8; ++j) acc[i][j] = fmaf(av[i], bv[j], acc[i][j]);
    }
    __syncthreads();
  }

  // ---- epilogue: bias (+relu), float4 stores ----
#pragma unroll
  for (int i = 0; i < 8; ++i) {
    int gr = brow + rm + (i < 4 ? i : 32 + (i - 4));
    if (gr >= nrows) continue;
    float o[8];
#pragma unroll
    for (int j = 0; j < 8; ++j) {
      int col = cn + (j < 4 ? j : 64 + (j - 4));
      float v = acc[i][j] + bias[bcol + col];
      if (RELU) v = fmaxf(v, 0.f);
      o[j] = v;
    }
    float* outp = C + (size_t)gr * HIDC + bcol;
    *(float4*)(outp + cn) = make_float4(o[0], o[1], o[2], o[3]);
    *(float4*)(outp + cn + 64) = make_float4(o[4], o[5], o[6], o[7]);
  }
}

extern "C" void kernel_launch(void* const* d_in, const int* in_sizes, int n_in,
                              void* d_out, int out_size, void* d_ws,
                              size_t ws_size, hipStream_t stream) {
  const float* x = (const float*)d_in[0];
  const int* ei = (const int*)d_in[1];
  const float* W1l = (const float*)d_in[2];
  const float* b1 = (const float*)d_in[3];
  const float* W1r = (const float*)d_in[4];
  const float* W2l = (const float*)d_in[5];
  const float* b2 = (const float*)d_in[6];
  const float* W2r = (const float*)d_in[7];
  float* out = (float*)d_out;

  const int N = in_sizes[0] / 128;  // 50000
  const int E = in_sizes[1] / 2;    // 800000
  const int* src = ei;
  const int* dst = ei + E;

  // workspace layout
  char* ws = (char*)d_ws;
  size_t off = 0;
  auto walloc = [&](size_t bytes) {
    void* p = ws + off;
    off += (bytes + 255) & ~(size_t)255;
    return p;
  };
  int* deg = (int*)walloc((size_t)N * 4);
  int* row_start = (int*)walloc((size_t)(N + 1) * 4);
  int* cursor = (int*)walloc((size_t)N * 4);
  int* esrc = (int*)walloc((size_t)E * 4);
  float* agg1 = (float*)walloc((size_t)N * 128 * 4);
  float* h = (float*)walloc((size_t)N * 256 * 4);
  float* agg2 = (float*)walloc((size_t)N * 256 * 4);
  (void)ws_size;
  (void)n_in;
  (void)out_size;

  const int BLK = 256;
  const int eblocks = (E + BLK - 1) / BLK;

  // ---- CSR build ----
  hipMemsetAsync(deg, 0, (size_t)N * 4, stream);
  deg_count_kernel<<<eblocks, BLK, 0, stream>>>(dst, deg, E, N);
  scan_kernel<<<1, 256, 0, stream>>>(deg, row_start, cursor, N);
  fill_kernel<<<eblocks, BLK, 0, stream>>>(src, dst, cursor, esrc, E, N);

  // ---- layer 1 ----
  {
    int groups_per_block = 256 / 32;
    int grid = (N + groups_per_block - 1) / groups_per_block;
    gather_mean_kernel<32><<<grid, BLK, 0, stream>>>((const float4*)x,
                                                     row_start, esrc, (float4*)agg1, N);
  }
  {
    dim3 grid((N + 63) / 64, HIDC / 128);
    sage_gemm<128, true><<<grid, 128, 0, stream>>>(agg1, x, W1l, W1r, b1, h, N);
  }

  // ---- layer 2 ----
  {
    int groups_per_block = 256 / 64;
    int grid = (N + groups_per_block - 1) / groups_per_block;
    gather_mean_kernel<64><<<grid, BLK, 0, stream>>>((const float4*)h,
                                                     row_start, esrc, (float4*)agg2, N);
  }
  {
    dim3 grid((N + 63) / 64, HIDC / 128);
    sage_gemm<256, false><<<grid, 128, 0, stream>>>(agg2, h, W2l, W2r, b2, out, N);
  }
}

// Round 3
// 607.230 us; speedup vs baseline: 1.2681x; 1.2681x over previous
//
#include <hip/hip_runtime.h>
#include <hip/hip_bf16.h>

// GraphSAGE 2-hop. CSR-gather aggregation + split-bf16 MFMA GEMMs.
//   deg/row_start/esrc : CSR build (int atomics)
//   x_hi/x_lo          : bf16 split planes of x        [N][128]
//   agg1_hi/lo         : mean gather of x              [N][128]
//   h_hi/lo            : relu([agg1,x]@[W1l;W1r]+b1)   [N][256] (split in epilogue)
//   agg2_hi/lo         : mean gather of h              [N][256]
//   out (fp32)         : [agg2,h]@[W2l;W2r]+b2
// GEMM: D = A*B with A = node rows [M][K] (k-contig), B = W^T rows [N][K]
// (k-contig, pre-transposed on device). 3-term split: AhiBhi+AhiBlo+AloBhi.

typedef __attribute__((ext_vector_type(8))) short bf16x8;
typedef __attribute__((ext_vector_type(4))) float f32x4;
typedef __attribute__((ext_vector_type(4))) short s16x4;

constexpr int HIDC = 256;

__device__ __forceinline__ short f2bf(float v) {
  __hip_bfloat16 h = __float2bfloat16(v);  // RNE
  return *reinterpret_cast<short*>(&h);
}
__device__ __forceinline__ float bf2f(short s) {
  unsigned int u = ((unsigned int)(unsigned short)s) << 16;
  float f;
  __builtin_memcpy(&f, &u, 4);
  return f;
}

// ---------------- CSR build ----------------
__global__ __launch_bounds__(256) void deg_count_kernel(
    const int* __restrict__ dst, int* __restrict__ deg, int E, int N) {
  int e = blockIdx.x * blockDim.x + threadIdx.x;
  if (e < E) {
    int d = dst[e];
    if ((unsigned)d < (unsigned)N) atomicAdd(&deg[d], 1);
  }
}

__global__ __launch_bounds__(256) void scan_kernel(
    const int* __restrict__ deg, int* __restrict__ row_start,
    int* __restrict__ cursor, int N) {
  __shared__ int sums[256];
  const int t = threadIdx.x;
  const int chunk = (N + 255) / 256;
  const int lo = t * chunk;
  const int hi = (lo + chunk < N) ? lo + chunk : N;
  int s = 0;
  for (int i = lo; i < hi; ++i) s += deg[i];
  sums[t] = s;
  __syncthreads();
  for (int off = 1; off < 256; off <<= 1) {
    int v = (t >= off) ? sums[t - off] : 0;
    __syncthreads();
    sums[t] += v;
    __syncthreads();
  }
  int base = (t == 0) ? 0 : sums[t - 1];
  for (int i = lo; i < hi; ++i) {
    row_start[i] = base;
    cursor[i] = base;
    base += deg[i];
  }
  if (t == 255) row_start[N] = sums[255];
}

__global__ __launch_bounds__(256) void fill_kernel(
    const int* __restrict__ src, const int* __restrict__ dst,
    int* __restrict__ cursor, int* __restrict__ esrc, int E, int N) {
  int e = blockIdx.x * blockDim.x + threadIdx.x;
  if (e < E) {
    int d = dst[e];
    if ((unsigned)d < (unsigned)N) {
      int p = atomicAdd(&cursor[d], 1);
      esrc[p] = src[e];
    }
  }
}

// ---------------- conversions ----------------
__global__ __launch_bounds__(256) void xconv_kernel(
    const float4* __restrict__ x, s16x4* __restrict__ hi,
    s16x4* __restrict__ lo, int total4) {
  int i = blockIdx.x * 256 + threadIdx.x;
  if (i >= total4) return;
  float4 v = x[i];
  s16x4 h, l;
  h.x = f2bf(v.x); l.x = f2bf(v.x - bf2f(h.x));
  h.y = f2bf(v.y); l.y = f2bf(v.y - bf2f(h.y));
  h.z = f2bf(v.z); l.z = f2bf(v.z - bf2f(h.z));
  h.w = f2bf(v.w); l.w = f2bf(v.w - bf2f(h.w));
  hi[i] = h;
  lo[i] = l;
}

// W [K][NN] fp32 -> Wt planes [NN][K] bf16 hi/lo
template <int K, int NN>
__global__ __launch_bounds__(256) void wconv_kernel(
    const float* __restrict__ W, short* __restrict__ Wt_hi,
    short* __restrict__ Wt_lo) {
  int tid = blockIdx.x * 256 + threadIdx.x;
  if (tid >= K * NN) return;
  int k = tid / NN, n = tid % NN;
  float v = W[tid];
  short hv = f2bf(v);
  Wt_hi[n * K + k] = hv;
  Wt_lo[n * K + k] = f2bf(v - bf2f(hv));
}

// ---------------- gathers ----------------
// layer1: 32 lanes/node, lane owns float4 chunk (4 of 128 feats)
__global__ __launch_bounds__(256) void gather1_kernel(
    const float4* __restrict__ xf, const int* __restrict__ row_start,
    const int* __restrict__ esrc, s16x4* __restrict__ ahi,
    s16x4* __restrict__ alo, int N) {
  int gid = (int)(((long long)blockIdx.x * 256 + threadIdx.x) >> 5);
  int l = threadIdx.x & 31;
  if (gid >= N) return;
  int lo_e = row_start[gid], hi_e = row_start[gid + 1];
  float4 acc = make_float4(0.f, 0.f, 0.f, 0.f);
  int e = lo_e;
  for (; e + 1 < hi_e; e += 2) {
    int s0 = esrc[e], s1 = esrc[e + 1];
    float4 v0 = xf[(size_t)s0 * 32 + l];
    float4 v1 = xf[(size_t)s1 * 32 + l];
    acc.x += v0.x + v1.x; acc.y += v0.y + v1.y;
    acc.z += v0.z + v1.z; acc.w += v0.w + v1.w;
  }
  if (e < hi_e) {
    float4 v0 = xf[(size_t)esrc[e] * 32 + l];
    acc.x += v0.x; acc.y += v0.y; acc.z += v0.z; acc.w += v0.w;
  }
  float inv = (hi_e > lo_e) ? 1.0f / (float)(hi_e - lo_e) : 0.0f;
  acc.x *= inv; acc.y *= inv; acc.z *= inv; acc.w *= inv;
  s16x4 h, l4;
  h.x = f2bf(acc.x); l4.x = f2bf(acc.x - bf2f(h.x));
  h.y = f2bf(acc.y); l4.y = f2bf(acc.y - bf2f(h.y));
  h.z = f2bf(acc.z); l4.z = f2bf(acc.z - bf2f(h.z));
  h.w = f2bf(acc.w); l4.w = f2bf(acc.w - bf2f(h.w));
  ahi[(size_t)gid * 32 + l] = h;
  alo[(size_t)gid * 32 + l] = l4;
}

// layer2: 32 lanes/node, lane owns 8 of 256 feats (16B per plane)
__global__ __launch_bounds__(256) void gather2_kernel(
    const short* __restrict__ hhi, const short* __restrict__ hlo,
    const int* __restrict__ row_start, const int* __restrict__ esrc,
    bf16x8* __restrict__ ahi, bf16x8* __restrict__ alo, int N) {
  int gid = (int)(((long long)blockIdx.x * 256 + threadIdx.x) >> 5);
  int l = threadIdx.x & 31;
  if (gid >= N) return;
  int lo_e = row_start[gid], hi_e = row_start[gid + 1];
  float acc[8];
#pragma unroll
  for (int j = 0; j < 8; ++j) acc[j] = 0.f;
  for (int e = lo_e; e < hi_e; ++e) {
    size_t base = (size_t)esrc[e] * HIDC + l * 8;
    bf16x8 vh = *(const bf16x8*)(hhi + base);
    bf16x8 vl = *(const bf16x8*)(hlo + base);
#pragma unroll
    for (int j = 0; j < 8; ++j) acc[j] += bf2f(vh[j]) + bf2f(vl[j]);
  }
  float inv = (hi_e > lo_e) ? 1.0f / (float)(hi_e - lo_e) : 0.0f;
  bf16x8 oh, ol;
#pragma unroll
  for (int j = 0; j < 8; ++j) {
    float v = acc[j] * inv;
    short hv = f2bf(v);
    oh[j] = hv;
    ol[j] = f2bf(v - bf2f(hv));
  }
  ahi[(size_t)gid * 32 + l] = oh;
  alo[(size_t)gid * 32 + l] = ol;
}

// ---------------- MFMA GEMM ----------------
// C[i,j] = (relu?)(sum_k A[i,k]Wl[k,j] + sum_k X[i,k]Wr[k,j] + bias[j])
// Virtual K = 2*K1. Tiles: BM=128, BN=128, BK=32. 4 waves, 64x64 per wave.
// LDS rows padded to 40 shorts (80B) so frag reads/writes are conflict-free.
template <int K1, bool RELU, bool OUTBF>
__global__ __launch_bounds__(256) void mfma_gemm(
    const short* __restrict__ Ahi, const short* __restrict__ Alo,
    const short* __restrict__ Xhi, const short* __restrict__ Xlo,
    const short* __restrict__ WLhi, const short* __restrict__ WLlo,
    const short* __restrict__ WRhi, const short* __restrict__ WRlo,
    const float* __restrict__ bias, float* __restrict__ Cf,
    short* __restrict__ Chi, short* __restrict__ Clo, int M) {
  __shared__ __align__(16) short As_hi[128][40];
  __shared__ __align__(16) short As_lo[128][40];
  __shared__ __align__(16) short Bs_hi[128][40];
  __shared__ __align__(16) short Bs_lo[128][40];

  const int tid = threadIdx.x;
  const int lane = tid & 63;
  const int w = tid >> 6;
  const int brow = blockIdx.y * 128;
  const int bcol = blockIdx.x * 128;
  const int wr = (w >> 1) * 64;
  const int wc = (w & 1) * 64;

  // staging map: 2 threads/row, each stages 2x16B per plane
  const int srow = tid >> 1;
  const int koff = (tid & 1) * 16;  // in shorts

  int arow = brow + srow;
  if (arow >= M) arow = M - 1;  // clamp (real data; stores guarded)
  const int bn = bcol + srow;

  f32x4 acc[4][4];
#pragma unroll
  for (int m = 0; m < 4; ++m)
#pragma unroll
    for (int n = 0; n < 4; ++n) acc[m][n] = (f32x4){0.f, 0.f, 0.f, 0.f};

  for (int k0 = 0; k0 < 2 * K1; k0 += 32) {
    const bool left = k0 < K1;
    const int kk = left ? k0 : k0 - K1;
    const short* __restrict__ Aph = left ? Ahi : Xhi;
    const short* __restrict__ Apl = left ? Alo : Xlo;
    const short* __restrict__ Bph = left ? WLhi : WRhi;
    const short* __restrict__ Bpl = left ? WLlo : WRlo;

    // global loads first (overlap with previous compute)
    size_t abase = (size_t)arow * K1 + kk + koff;
    size_t bbase = (size_t)bn * K1 + kk + koff;
    bf16x8 ga0 = *(const bf16x8*)(Aph + abase);
    bf16x8 ga1 = *(const bf16x8*)(Aph + abase + 8);
    bf16x8 ga2 = *(const bf16x8*)(Apl + abase);
    bf16x8 ga3 = *(const bf16x8*)(Apl + abase + 8);
    bf16x8 gb0 = *(const bf16x8*)(Bph + bbase);
    bf16x8 gb1 = *(const bf16x8*)(Bph + bbase + 8);
    bf16x8 gb2 = *(const bf16x8*)(Bpl + bbase);
    bf16x8 gb3 = *(const bf16x8*)(Bpl + bbase + 8);

    __syncthreads();  // previous iteration's frag reads complete
    *(bf16x8*)&As_hi[srow][koff] = ga0;
    *(bf16x8*)&As_hi[srow][koff + 8] = ga1;
    *(bf16x8*)&As_lo[srow][koff] = ga2;
    *(bf16x8*)&As_lo[srow][koff + 8] = ga3;
    *(bf16x8*)&Bs_hi[srow][koff] = gb0;
    *(bf16x8*)&Bs_hi[srow][koff + 8] = gb1;
    *(bf16x8*)&Bs_lo[srow][koff] = gb2;
    *(bf16x8*)&Bs_lo[srow][koff + 8] = gb3;
    __syncthreads();

    const int fr = lane & 15;
    const int fk = (lane >> 4) * 8;
    bf16x8 ah[4], al[4], bh[4], bl[4];
#pragma unroll
    for (int m = 0; m < 4; ++m) {
      ah[m] = *(const bf16x8*)&As_hi[wr + m * 16 + fr][fk];
      al[m] = *(const bf16x8*)&As_lo[wr + m * 16 + fr][fk];
    }
#pragma unroll
    for (int n = 0; n < 4; ++n) {
      bh[n] = *(const bf16x8*)&Bs_hi[wc + n * 16 + fr][fk];
      bl[n] = *(const bf16x8*)&Bs_lo[wc + n * 16 + fr][fk];
    }
#pragma unroll
    for (int m = 0; m < 4; ++m)
#pragma unroll
      for (int n = 0; n < 4; ++n) {
        acc[m][n] = __builtin_amdgcn_mfma_f32_16x16x32_bf16(ah[m], bh[n],
                                                            acc[m][n], 0, 0, 0);
        acc[m][n] = __builtin_amdgcn_mfma_f32_16x16x32_bf16(ah[m], bl[n],
                                                            acc[m][n], 0, 0, 0);
        acc[m][n] = __builtin_amdgcn_mfma_f32_16x16x32_bf16(al[m], bh[n],
                                                            acc[m][n], 0, 0, 0);
      }
  }

  // epilogue: C/D layout col=lane&15, row=(lane>>4)*4+j  [m89/m91 verified]
  const int lcol = lane & 15;
  const int lrow = (lane >> 4) * 4;
#pragma unroll
  for (int m = 0; m < 4; ++m) {
    int gr0 = brow + wr + m * 16 + lrow;
#pragma unroll
    for (int n = 0; n < 4; ++n) {
      int gc = bcol + wc + n * 16 + lcol;
      float bv = bias[gc];
#pragma unroll
      for (int j = 0; j < 4; ++j) {
        int gr = gr0 + j;
        if (gr >= M) continue;
        float v = acc[m][n][j] + bv;
        if (RELU) v = fmaxf(v, 0.f);
        if (OUTBF) {
          short hv = f2bf(v);
          Chi[(size_t)gr * HIDC + gc] = hv;
          Clo[(size_t)gr * HIDC + gc] = f2bf(v - bf2f(hv));
        } else {
          Cf[(size_t)gr * HIDC + gc] = v;
        }
      }
    }
  }
}

extern "C" void kernel_launch(void* const* d_in, const int* in_sizes, int n_in,
                              void* d_out, int out_size, void* d_ws,
                              size_t ws_size, hipStream_t stream) {
  const float* x = (const float*)d_in[0];
  const int* ei = (const int*)d_in[1];
  const float* W1l = (const float*)d_in[2];
  const float* b1 = (const float*)d_in[3];
  const float* W1r = (const float*)d_in[4];
  const float* W2l = (const float*)d_in[5];
  const float* b2 = (const float*)d_in[6];
  const float* W2r = (const float*)d_in[7];
  float* out = (float*)d_out;

  const int N = in_sizes[0] / 128;  // 50000
  const int E = in_sizes[1] / 2;    // 800000
  const int* src = ei;
  const int* dst = ei + E;

  char* ws = (char*)d_ws;
  size_t off = 0;
  auto walloc = [&](size_t bytes) {
    void* p = ws + off;
    off += (bytes + 255) & ~(size_t)255;
    return p;
  };
  int* deg = (int*)walloc((size_t)N * 4);
  int* row_start = (int*)walloc((size_t)(N + 1) * 4);
  int* cursor = (int*)walloc((size_t)N * 4);
  int* esrc = (int*)walloc((size_t)E * 4);
  short* x_hi = (short*)walloc((size_t)N * 128 * 2);
  short* x_lo = (short*)walloc((size_t)N * 128 * 2);
  short* agg1_hi = (short*)walloc((size_t)N * 128 * 2);
  short* agg1_lo = (short*)walloc((size_t)N * 128 * 2);
  short* h_hi = (short*)walloc((size_t)N * 256 * 2);
  short* h_lo = (short*)walloc((size_t)N * 256 * 2);
  short* agg2_hi = (short*)walloc((size_t)N * 256 * 2);
  short* agg2_lo = (short*)walloc((size_t)N * 256 * 2);
  short* Wt1l_hi = (short*)walloc(128 * 256 * 2);
  short* Wt1l_lo = (short*)walloc(128 * 256 * 2);
  short* Wt1r_hi = (short*)walloc(128 * 256 * 2);
  short* Wt1r_lo = (short*)walloc(128 * 256 * 2);
  short* Wt2l_hi = (short*)walloc(256 * 256 * 2);
  short* Wt2l_lo = (short*)walloc(256 * 256 * 2);
  short* Wt2r_hi = (short*)walloc(256 * 256 * 2);
  short* Wt2r_lo = (short*)walloc(256 * 256 * 2);
  (void)ws_size;
  (void)n_in;
  (void)out_size;

  const int BLK = 256;
  const int eblocks = (E + BLK - 1) / BLK;

  // conversions (independent of CSR)
  xconv_kernel<<<(N * 32 + BLK - 1) / BLK, BLK, 0, stream>>>(
      (const float4*)x, (s16x4*)x_hi, (s16x4*)x_lo, N * 32);
  wconv_kernel<128, 256><<<(128 * 256 + BLK - 1) / BLK, BLK, 0, stream>>>(
      W1l, Wt1l_hi, Wt1l_lo);
  wconv_kernel<128, 256><<<(128 * 256 + BLK - 1) / BLK, BLK, 0, stream>>>(
      W1r, Wt1r_hi, Wt1r_lo);
  wconv_kernel<256, 256><<<(256 * 256 + BLK - 1) / BLK, BLK, 0, stream>>>(
      W2l, Wt2l_hi, Wt2l_lo);
  wconv_kernel<256, 256><<<(256 * 256 + BLK - 1) / BLK, BLK, 0, stream>>>(
      W2r, Wt2r_hi, Wt2r_lo);

  // CSR build
  hipMemsetAsync(deg, 0, (size_t)N * 4, stream);
  deg_count_kernel<<<eblocks, BLK, 0, stream>>>(dst, deg, E, N);
  scan_kernel<<<1, 256, 0, stream>>>(deg, row_start, cursor, N);
  fill_kernel<<<eblocks, BLK, 0, stream>>>(src, dst, cursor, esrc, E, N);

  // layer 1
  gather1_kernel<<<(N * 32 + BLK - 1) / BLK, BLK, 0, stream>>>(
      (const float4*)x, row_start, esrc, (s16x4*)agg1_hi, (s16x4*)agg1_lo, N);
  {
    dim3 grid(2, (N + 127) / 128);
    mfma_gemm<128, true, true><<<grid, BLK, 0, stream>>>(
        agg1_hi, agg1_lo, x_hi, x_lo, Wt1l_hi, Wt1l_lo, Wt1r_hi, Wt1r_lo, b1,
        nullptr, h_hi, h_lo, N);
  }

  // layer 2
  gather2_kernel<<<(N * 32 + BLK - 1) / BLK, BLK, 0, stream>>>(
      h_hi, h_lo, row_start, esrc, (bf16x8*)agg2_hi, (bf16x8*)agg2_lo, N);
  {
    dim3 grid(2, (N + 127) / 128);
    mfma_gemm<256, false, false><<<grid, BLK, 0, stream>>>(
        agg2_hi, agg2_lo, h_hi, h_lo, Wt2l_hi, Wt2l_lo, Wt2r_hi, Wt2r_lo, b2,
        out, nullptr, nullptr, N);
  }
}

// Round 4
// 487.001 us; speedup vs baseline: 1.5812x; 1.2469x over previous
//
#include <hip/hip_runtime.h>
#include <hip/hip_bf16.h>

// GraphSAGE 2-hop. CSR-gather aggregation + split-bf16 MFMA GEMMs.
// R3 change: single-block scan_kernel (121us, serial bottleneck) replaced by
// 3-phase parallel scan (blocksum -> scan partials -> scatter offsets).

typedef __attribute__((ext_vector_type(8))) short bf16x8;
typedef __attribute__((ext_vector_type(4))) float f32x4;
typedef __attribute__((ext_vector_type(4))) short s16x4;

constexpr int HIDC = 256;

__device__ __forceinline__ short f2bf(float v) {
  __hip_bfloat16 h = __float2bfloat16(v);  // RNE
  return *reinterpret_cast<short*>(&h);
}
__device__ __forceinline__ float bf2f(short s) {
  unsigned int u = ((unsigned int)(unsigned short)s) << 16;
  float f;
  __builtin_memcpy(&f, &u, 4);
  return f;
}

// ---------------- CSR build ----------------
__global__ __launch_bounds__(256) void deg_count_kernel(
    const int* __restrict__ dst, int* __restrict__ deg, int E, int N) {
  int e = blockIdx.x * blockDim.x + threadIdx.x;
  if (e < E) {
    int d = dst[e];
    if ((unsigned)d < (unsigned)N) atomicAdd(&deg[d], 1);
  }
}

// Phase A: per-block sums of deg (256 elements per block, coalesced)
__global__ __launch_bounds__(256) void blocksum_kernel(
    const int* __restrict__ deg, int* __restrict__ bsum, int N) {
  __shared__ int red[256];
  int i = blockIdx.x * 256 + threadIdx.x;
  red[threadIdx.x] = (i < N) ? deg[i] : 0;
  __syncthreads();
#pragma unroll
  for (int off = 128; off > 0; off >>= 1) {
    if (threadIdx.x < off) red[threadIdx.x] += red[threadIdx.x + off];
    __syncthreads();
  }
  if (threadIdx.x == 0) bsum[blockIdx.x] = red[0];
}

// Phase B: one block scans the <=256 block partials -> exclusive offsets,
// and writes row_start[N] = total.
__global__ __launch_bounds__(256) void bscan_kernel(
    const int* __restrict__ bsum, int* __restrict__ boff,
    int* __restrict__ row_start, int nb, int N) {
  __shared__ int s[256];
  int t = threadIdx.x;
  s[t] = (t < nb) ? bsum[t] : 0;
  __syncthreads();
  for (int off = 1; off < 256; off <<= 1) {
    int v = (t >= off) ? s[t - off] : 0;
    __syncthreads();
    s[t] += v;
    __syncthreads();
  }
  if (t < nb) boff[t] = (t == 0) ? 0 : s[t - 1];
  if (t == nb - 1) row_start[N] = s[t];
}

// Phase C: in-block exclusive scan + block offset -> row_start & cursor
__global__ __launch_bounds__(256) void scatter_offsets_kernel(
    const int* __restrict__ deg, const int* __restrict__ boff,
    int* __restrict__ row_start, int* __restrict__ cursor, int N) {
  __shared__ int s[256];
  int i = blockIdx.x * 256 + threadIdx.x;
  int t = threadIdx.x;
  int v = (i < N) ? deg[i] : 0;
  s[t] = v;
  __syncthreads();
  for (int off = 1; off < 256; off <<= 1) {
    int u = (t >= off) ? s[t - off] : 0;
    __syncthreads();
    s[t] += u;
    __syncthreads();
  }
  if (i < N) {
    int excl = s[t] - v + boff[blockIdx.x];
    row_start[i] = excl;
    cursor[i] = excl;
  }
}

__global__ __launch_bounds__(256) void fill_kernel(
    const int* __restrict__ src, const int* __restrict__ dst,
    int* __restrict__ cursor, int* __restrict__ esrc, int E, int N) {
  int e = blockIdx.x * blockDim.x + threadIdx.x;
  if (e < E) {
    int d = dst[e];
    if ((unsigned)d < (unsigned)N) {
      int p = atomicAdd(&cursor[d], 1);
      esrc[p] = src[e];
    }
  }
}

// ---------------- conversions ----------------
__global__ __launch_bounds__(256) void xconv_kernel(
    const float4* __restrict__ x, s16x4* __restrict__ hi,
    s16x4* __restrict__ lo, int total4) {
  int i = blockIdx.x * 256 + threadIdx.x;
  if (i >= total4) return;
  float4 v = x[i];
  s16x4 h, l;
  h.x = f2bf(v.x); l.x = f2bf(v.x - bf2f(h.x));
  h.y = f2bf(v.y); l.y = f2bf(v.y - bf2f(h.y));
  h.z = f2bf(v.z); l.z = f2bf(v.z - bf2f(h.z));
  h.w = f2bf(v.w); l.w = f2bf(v.w - bf2f(h.w));
  hi[i] = h;
  lo[i] = l;
}

// W [K][NN] fp32 -> Wt planes [NN][K] bf16 hi/lo
template <int K, int NN>
__global__ __launch_bounds__(256) void wconv_kernel(
    const float* __restrict__ W, short* __restrict__ Wt_hi,
    short* __restrict__ Wt_lo) {
  int tid = blockIdx.x * 256 + threadIdx.x;
  if (tid >= K * NN) return;
  int k = tid / NN, n = tid % NN;
  float v = W[tid];
  short hv = f2bf(v);
  Wt_hi[n * K + k] = hv;
  Wt_lo[n * K + k] = f2bf(v - bf2f(hv));
}

// ---------------- gathers ----------------
// layer1: 32 lanes/node, lane owns float4 chunk (4 of 128 feats)
__global__ __launch_bounds__(256) void gather1_kernel(
    const float4* __restrict__ xf, const int* __restrict__ row_start,
    const int* __restrict__ esrc, s16x4* __restrict__ ahi,
    s16x4* __restrict__ alo, int N) {
  int gid = (int)(((long long)blockIdx.x * 256 + threadIdx.x) >> 5);
  int l = threadIdx.x & 31;
  if (gid >= N) return;
  int lo_e = row_start[gid], hi_e = row_start[gid + 1];
  float4 acc = make_float4(0.f, 0.f, 0.f, 0.f);
  int e = lo_e;
  for (; e + 1 < hi_e; e += 2) {
    int s0 = esrc[e], s1 = esrc[e + 1];
    float4 v0 = xf[(size_t)s0 * 32 + l];
    float4 v1 = xf[(size_t)s1 * 32 + l];
    acc.x += v0.x + v1.x; acc.y += v0.y + v1.y;
    acc.z += v0.z + v1.z; acc.w += v0.w + v1.w;
  }
  if (e < hi_e) {
    float4 v0 = xf[(size_t)esrc[e] * 32 + l];
    acc.x += v0.x; acc.y += v0.y; acc.z += v0.z; acc.w += v0.w;
  }
  float inv = (hi_e > lo_e) ? 1.0f / (float)(hi_e - lo_e) : 0.0f;
  acc.x *= inv; acc.y *= inv; acc.z *= inv; acc.w *= inv;
  s16x4 h, l4;
  h.x = f2bf(acc.x); l4.x = f2bf(acc.x - bf2f(h.x));
  h.y = f2bf(acc.y); l4.y = f2bf(acc.y - bf2f(h.y));
  h.z = f2bf(acc.z); l4.z = f2bf(acc.z - bf2f(h.z));
  h.w = f2bf(acc.w); l4.w = f2bf(acc.w - bf2f(h.w));
  ahi[(size_t)gid * 32 + l] = h;
  alo[(size_t)gid * 32 + l] = l4;
}

// layer2: 32 lanes/node, lane owns 8 of 256 feats (16B per plane)
__global__ __launch_bounds__(256) void gather2_kernel(
    const short* __restrict__ hhi, const short* __restrict__ hlo,
    const int* __restrict__ row_start, const int* __restrict__ esrc,
    bf16x8* __restrict__ ahi, bf16x8* __restrict__ alo, int N) {
  int gid = (int)(((long long)blockIdx.x * 256 + threadIdx.x) >> 5);
  int l = threadIdx.x & 31;
  if (gid >= N) return;
  int lo_e = row_start[gid], hi_e = row_start[gid + 1];
  float acc[8];
#pragma unroll
  for (int j = 0; j < 8; ++j) acc[j] = 0.f;
  for (int e = lo_e; e < hi_e; ++e) {
    size_t base = (size_t)esrc[e] * HIDC + l * 8;
    bf16x8 vh = *(const bf16x8*)(hhi + base);
    bf16x8 vl = *(const bf16x8*)(hlo + base);
#pragma unroll
    for (int j = 0; j < 8; ++j) acc[j] += bf2f(vh[j]) + bf2f(vl[j]);
  }
  float inv = (hi_e > lo_e) ? 1.0f / (float)(hi_e - lo_e) : 0.0f;
  bf16x8 oh, ol;
#pragma unroll
  for (int j = 0; j < 8; ++j) {
    float v = acc[j] * inv;
    short hv = f2bf(v);
    oh[j] = hv;
    ol[j] = f2bf(v - bf2f(hv));
  }
  ahi[(size_t)gid * 32 + l] = oh;
  alo[(size_t)gid * 32 + l] = ol;
}

// ---------------- MFMA GEMM ----------------
// C[i,j] = (relu?)(sum_k A[i,k]Wl[k,j] + sum_k X[i,k]Wr[k,j] + bias[j])
// Virtual K = 2*K1. Tiles: BM=128, BN=128, BK=32. 4 waves, 64x64 per wave.
template <int K1, bool RELU, bool OUTBF>
__global__ __launch_bounds__(256) void mfma_gemm(
    const short* __restrict__ Ahi, const short* __restrict__ Alo,
    const short* __restrict__ Xhi, const short* __restrict__ Xlo,
    const short* __restrict__ WLhi, const short* __restrict__ WLlo,
    const short* __restrict__ WRhi, const short* __restrict__ WRlo,
    const float* __restrict__ bias, float* __restrict__ Cf,
    short* __restrict__ Chi, short* __restrict__ Clo, int M) {
  __shared__ __align__(16) short As_hi[128][40];
  __shared__ __align__(16) short As_lo[128][40];
  __shared__ __align__(16) short Bs_hi[128][40];
  __shared__ __align__(16) short Bs_lo[128][40];

  const int tid = threadIdx.x;
  const int lane = tid & 63;
  const int w = tid >> 6;
  const int brow = blockIdx.y * 128;
  const int bcol = blockIdx.x * 128;
  const int wr = (w >> 1) * 64;
  const int wc = (w & 1) * 64;

  // staging map: 2 threads/row, each stages 2x16B per plane
  const int srow = tid >> 1;
  const int koff = (tid & 1) * 16;  // in shorts

  int arow = brow + srow;
  if (arow >= M) arow = M - 1;  // clamp (real data; stores guarded)
  const int bn = bcol + srow;

  f32x4 acc[4][4];
#pragma unroll
  for (int m = 0; m < 4; ++m)
#pragma unroll
    for (int n = 0; n < 4; ++n) acc[m][n] = (f32x4){0.f, 0.f, 0.f, 0.f};

  for (int k0 = 0; k0 < 2 * K1; k0 += 32) {
    const bool left = k0 < K1;
    const int kk = left ? k0 : k0 - K1;
    const short* __restrict__ Aph = left ? Ahi : Xhi;
    const short* __restrict__ Apl = left ? Alo : Xlo;
    const short* __restrict__ Bph = left ? WLhi : WRhi;
    const short* __restrict__ Bpl = left ? WLlo : WRlo;

    // global loads first (overlap with previous compute)
    size_t abase = (size_t)arow * K1 + kk + koff;
    size_t bbase = (size_t)bn * K1 + kk + koff;
    bf16x8 ga0 = *(const bf16x8*)(Aph + abase);
    bf16x8 ga1 = *(const bf16x8*)(Aph + abase + 8);
    bf16x8 ga2 = *(const bf16x8*)(Apl + abase);
    bf16x8 ga3 = *(const bf16x8*)(Apl + abase + 8);
    bf16x8 gb0 = *(const bf16x8*)(Bph + bbase);
    bf16x8 gb1 = *(const bf16x8*)(Bph + bbase + 8);
    bf16x8 gb2 = *(const bf16x8*)(Bpl + bbase);
    bf16x8 gb3 = *(const bf16x8*)(Bpl + bbase + 8);

    __syncthreads();  // previous iteration's frag reads complete
    *(bf16x8*)&As_hi[srow][koff] = ga0;
    *(bf16x8*)&As_hi[srow][koff + 8] = ga1;
    *(bf16x8*)&As_lo[srow][koff] = ga2;
    *(bf16x8*)&As_lo[srow][koff + 8] = ga3;
    *(bf16x8*)&Bs_hi[srow][koff] = gb0;
    *(bf16x8*)&Bs_hi[srow][koff + 8] = gb1;
    *(bf16x8*)&Bs_lo[srow][koff] = gb2;
    *(bf16x8*)&Bs_lo[srow][koff + 8] = gb3;
    __syncthreads();

    const int fr = lane & 15;
    const int fk = (lane >> 4) * 8;
    bf16x8 ah[4], al[4], bh[4], bl[4];
#pragma unroll
    for (int m = 0; m < 4; ++m) {
      ah[m] = *(const bf16x8*)&As_hi[wr + m * 16 + fr][fk];
      al[m] = *(const bf16x8*)&As_lo[wr + m * 16 + fr][fk];
    }
#pragma unroll
    for (int n = 0; n < 4; ++n) {
      bh[n] = *(const bf16x8*)&Bs_hi[wc + n * 16 + fr][fk];
      bl[n] = *(const bf16x8*)&Bs_lo[wc + n * 16 + fr][fk];
    }
#pragma unroll
    for (int m = 0; m < 4; ++m)
#pragma unroll
      for (int n = 0; n < 4; ++n) {
        acc[m][n] = __builtin_amdgcn_mfma_f32_16x16x32_bf16(ah[m], bh[n],
                                                            acc[m][n], 0, 0, 0);
        acc[m][n] = __builtin_amdgcn_mfma_f32_16x16x32_bf16(ah[m], bl[n],
                                                            acc[m][n], 0, 0, 0);
        acc[m][n] = __builtin_amdgcn_mfma_f32_16x16x32_bf16(al[m], bh[n],
                                                            acc[m][n], 0, 0, 0);
      }
  }

  // epilogue: C/D layout col=lane&15, row=(lane>>4)*4+j  [m89/m91 verified]
  const int lcol = lane & 15;
  const int lrow = (lane >> 4) * 4;
#pragma unroll
  for (int m = 0; m < 4; ++m) {
    int gr0 = brow + wr + m * 16 + lrow;
#pragma unroll
    for (int n = 0; n < 4; ++n) {
      int gc = bcol + wc + n * 16 + lcol;
      float bv = bias[gc];
#pragma unroll
      for (int j = 0; j < 4; ++j) {
        int gr = gr0 + j;
        if (gr >= M) continue;
        float v = acc[m][n][j] + bv;
        if (RELU) v = fmaxf(v, 0.f);
        if (OUTBF) {
          short hv = f2bf(v);
          Chi[(size_t)gr * HIDC + gc] = hv;
          Clo[(size_t)gr * HIDC + gc] = f2bf(v - bf2f(hv));
        } else {
          Cf[(size_t)gr * HIDC + gc] = v;
        }
      }
    }
  }
}

extern "C" void kernel_launch(void* const* d_in, const int* in_sizes, int n_in,
                              void* d_out, int out_size, void* d_ws,
                              size_t ws_size, hipStream_t stream) {
  const float* x = (const float*)d_in[0];
  const int* ei = (const int*)d_in[1];
  const float* W1l = (const float*)d_in[2];
  const float* b1 = (const float*)d_in[3];
  const float* W1r = (const float*)d_in[4];
  const float* W2l = (const float*)d_in[5];
  const float* b2 = (const float*)d_in[6];
  const float* W2r = (const float*)d_in[7];
  float* out = (float*)d_out;

  const int N = in_sizes[0] / 128;  // 50000
  const int E = in_sizes[1] / 2;    // 800000
  const int* src = ei;
  const int* dst = ei + E;

  char* ws = (char*)d_ws;
  size_t off = 0;
  auto walloc = [&](size_t bytes) {
    void* p = ws + off;
    off += (bytes + 255) & ~(size_t)255;
    return p;
  };
  int* deg = (int*)walloc((size_t)N * 4);
  int* row_start = (int*)walloc((size_t)(N + 1) * 4);
  int* cursor = (int*)walloc((size_t)N * 4);
  int* esrc = (int*)walloc((size_t)E * 4);
  int* bsum = (int*)walloc(256 * 4);
  int* boff = (int*)walloc(256 * 4);
  short* x_hi = (short*)walloc((size_t)N * 128 * 2);
  short* x_lo = (short*)walloc((size_t)N * 128 * 2);
  short* agg1_hi = (short*)walloc((size_t)N * 128 * 2);
  short* agg1_lo = (short*)walloc((size_t)N * 128 * 2);
  short* h_hi = (short*)walloc((size_t)N * 256 * 2);
  short* h_lo = (short*)walloc((size_t)N * 256 * 2);
  short* agg2_hi = (short*)walloc((size_t)N * 256 * 2);
  short* agg2_lo = (short*)walloc((size_t)N * 256 * 2);
  short* Wt1l_hi = (short*)walloc(128 * 256 * 2);
  short* Wt1l_lo = (short*)walloc(128 * 256 * 2);
  short* Wt1r_hi = (short*)walloc(128 * 256 * 2);
  short* Wt1r_lo = (short*)walloc(128 * 256 * 2);
  short* Wt2l_hi = (short*)walloc(256 * 256 * 2);
  short* Wt2l_lo = (short*)walloc(256 * 256 * 2);
  short* Wt2r_hi = (short*)walloc(256 * 256 * 2);
  short* Wt2r_lo = (short*)walloc(256 * 256 * 2);
  (void)ws_size;
  (void)n_in;
  (void)out_size;

  const int BLK = 256;
  const int eblocks = (E + BLK - 1) / BLK;
  const int nblocks = (N + BLK - 1) / BLK;  // 196

  // conversions (independent of CSR)
  xconv_kernel<<<(N * 32 + BLK - 1) / BLK, BLK, 0, stream>>>(
      (const float4*)x, (s16x4*)x_hi, (s16x4*)x_lo, N * 32);
  wconv_kernel<128, 256><<<(128 * 256 + BLK - 1) / BLK, BLK, 0, stream>>>(
      W1l, Wt1l_hi, Wt1l_lo);
  wconv_kernel<128, 256><<<(128 * 256 + BLK - 1) / BLK, BLK, 0, stream>>>(
      W1r, Wt1r_hi, Wt1r_lo);
  wconv_kernel<256, 256><<<(256 * 256 + BLK - 1) / BLK, BLK, 0, stream>>>(
      W2l, Wt2l_hi, Wt2l_lo);
  wconv_kernel<256, 256><<<(256 * 256 + BLK - 1) / BLK, BLK, 0, stream>>>(
      W2r, Wt2r_hi, Wt2r_lo);

  // CSR build (3-phase parallel scan)
  hipMemsetAsync(deg, 0, (size_t)N * 4, stream);
  deg_count_kernel<<<eblocks, BLK, 0, stream>>>(dst, deg, E, N);
  blocksum_kernel<<<nblocks, BLK, 0, stream>>>(deg, bsum, N);
  bscan_kernel<<<1, 256, 0, stream>>>(bsum, boff, row_start, nblocks, N);
  scatter_offsets_kernel<<<nblocks, BLK, 0, stream>>>(deg, boff, row_start,
                                                      cursor, N);
  fill_kernel<<<eblocks, BLK, 0, stream>>>(src, dst, cursor, esrc, E, N);

  // layer 1
  gather1_kernel<<<(N * 32 + BLK - 1) / BLK, BLK, 0, stream>>>(
      (const float4*)x, row_start, esrc, (s16x4*)agg1_hi, (s16x4*)agg1_lo, N);
  {
    dim3 grid(2, (N + 127) / 128);
    mfma_gemm<128, true, true><<<grid, BLK, 0, stream>>>(
        agg1_hi, agg1_lo, x_hi, x_lo, Wt1l_hi, Wt1l_lo, Wt1r_hi, Wt1r_lo, b1,
        nullptr, h_hi, h_lo, N);
  }

  // layer 2
  gather2_kernel<<<(N * 32 + BLK - 1) / BLK, BLK, 0, stream>>>(
      h_hi, h_lo, row_start, esrc, (bf16x8*)agg2_hi, (bf16x8*)agg2_lo, N);
  {
    dim3 grid(2, (N + 127) / 128);
    mfma_gemm<256, false, false><<<grid, BLK, 0, stream>>>(
        agg2_hi, agg2_lo, h_hi, h_lo, Wt2l_hi, Wt2l_lo, Wt2r_hi, Wt2r_lo, b2,
        out, nullptr, nullptr, N);
  }
}

// Round 5
// 420.079 us; speedup vs baseline: 1.8331x; 1.1593x over previous
//
#include <hip/hip_runtime.h>
#include <hip/hip_bf16.h>

// GraphSAGE 2-hop. CSR-gather aggregation + split-bf16 MFMA GEMMs.
// R4 change: gathers read bf16 hi-plane only (halves gather traffic; the
// mean-of-~16 bf16 rounding adds ~1e-3 error, well under absmax budget).
// gather1: 16 lanes/node over x_hi[128]; gather2: 32 lanes/node over h_hi[256].

typedef __attribute__((ext_vector_type(8))) short bf16x8;
typedef __attribute__((ext_vector_type(4))) float f32x4;
typedef __attribute__((ext_vector_type(4))) short s16x4;

constexpr int HIDC = 256;

__device__ __forceinline__ short f2bf(float v) {
  __hip_bfloat16 h = __float2bfloat16(v);  // RNE
  return *reinterpret_cast<short*>(&h);
}
__device__ __forceinline__ float bf2f(short s) {
  unsigned int u = ((unsigned int)(unsigned short)s) << 16;
  float f;
  __builtin_memcpy(&f, &u, 4);
  return f;
}

// ---------------- CSR build ----------------
__global__ __launch_bounds__(256) void deg_count_kernel(
    const int* __restrict__ dst, int* __restrict__ deg, int E, int N) {
  int e = blockIdx.x * blockDim.x + threadIdx.x;
  if (e < E) {
    int d = dst[e];
    if ((unsigned)d < (unsigned)N) atomicAdd(&deg[d], 1);
  }
}

// Phase A: per-block sums of deg (256 elements per block, coalesced)
__global__ __launch_bounds__(256) void blocksum_kernel(
    const int* __restrict__ deg, int* __restrict__ bsum, int N) {
  __shared__ int red[256];
  int i = blockIdx.x * 256 + threadIdx.x;
  red[threadIdx.x] = (i < N) ? deg[i] : 0;
  __syncthreads();
#pragma unroll
  for (int off = 128; off > 0; off >>= 1) {
    if (threadIdx.x < off) red[threadIdx.x] += red[threadIdx.x + off];
    __syncthreads();
  }
  if (threadIdx.x == 0) bsum[blockIdx.x] = red[0];
}

// Phase B: one block scans the <=256 block partials -> exclusive offsets,
// and writes row_start[N] = total.
__global__ __launch_bounds__(256) void bscan_kernel(
    const int* __restrict__ bsum, int* __restrict__ boff,
    int* __restrict__ row_start, int nb, int N) {
  __shared__ int s[256];
  int t = threadIdx.x;
  s[t] = (t < nb) ? bsum[t] : 0;
  __syncthreads();
  for (int off = 1; off < 256; off <<= 1) {
    int v = (t >= off) ? s[t - off] : 0;
    __syncthreads();
    s[t] += v;
    __syncthreads();
  }
  if (t < nb) boff[t] = (t == 0) ? 0 : s[t - 1];
  if (t == nb - 1) row_start[N] = s[t];
}

// Phase C: in-block exclusive scan + block offset -> row_start & cursor
__global__ __launch_bounds__(256) void scatter_offsets_kernel(
    const int* __restrict__ deg, const int* __restrict__ boff,
    int* __restrict__ row_start, int* __restrict__ cursor, int N) {
  __shared__ int s[256];
  int i = blockIdx.x * 256 + threadIdx.x;
  int t = threadIdx.x;
  int v = (i < N) ? deg[i] : 0;
  s[t] = v;
  __syncthreads();
  for (int off = 1; off < 256; off <<= 1) {
    int u = (t >= off) ? s[t - off] : 0;
    __syncthreads();
    s[t] += u;
    __syncthreads();
  }
  if (i < N) {
    int excl = s[t] - v + boff[blockIdx.x];
    row_start[i] = excl;
    cursor[i] = excl;
  }
}

__global__ __launch_bounds__(256) void fill_kernel(
    const int* __restrict__ src, const int* __restrict__ dst,
    int* __restrict__ cursor, int* __restrict__ esrc, int E, int N) {
  int e = blockIdx.x * blockDim.x + threadIdx.x;
  if (e < E) {
    int d = dst[e];
    if ((unsigned)d < (unsigned)N) {
      int p = atomicAdd(&cursor[d], 1);
      esrc[p] = src[e];
    }
  }
}

// ---------------- conversions ----------------
__global__ __launch_bounds__(256) void xconv_kernel(
    const float4* __restrict__ x, s16x4* __restrict__ hi,
    s16x4* __restrict__ lo, int total4) {
  int i = blockIdx.x * 256 + threadIdx.x;
  if (i >= total4) return;
  float4 v = x[i];
  s16x4 h, l;
  h.x = f2bf(v.x); l.x = f2bf(v.x - bf2f(h.x));
  h.y = f2bf(v.y); l.y = f2bf(v.y - bf2f(h.y));
  h.z = f2bf(v.z); l.z = f2bf(v.z - bf2f(h.z));
  h.w = f2bf(v.w); l.w = f2bf(v.w - bf2f(h.w));
  hi[i] = h;
  lo[i] = l;
}

// W [K][NN] fp32 -> Wt planes [NN][K] bf16 hi/lo
template <int K, int NN>
__global__ __launch_bounds__(256) void wconv_kernel(
    const float* __restrict__ W, short* __restrict__ Wt_hi,
    short* __restrict__ Wt_lo) {
  int tid = blockIdx.x * 256 + threadIdx.x;
  if (tid >= K * NN) return;
  int k = tid / NN, n = tid % NN;
  float v = W[tid];
  short hv = f2bf(v);
  Wt_hi[n * K + k] = hv;
  Wt_lo[n * K + k] = f2bf(v - bf2f(hv));
}

// ---------------- gathers ----------------
// layer1: 16 lanes/node; lane owns 8 of 128 feats (16B). Reads x_hi only.
__global__ __launch_bounds__(256) void gather1_kernel(
    const short* __restrict__ xhi, const int* __restrict__ row_start,
    const int* __restrict__ esrc, short* __restrict__ ahi,
    short* __restrict__ alo, int N) {
  int gid = (int)(((long long)blockIdx.x * 256 + threadIdx.x) >> 4);
  int l = threadIdx.x & 15;
  if (gid >= N) return;
  int lo_e = row_start[gid], hi_e = row_start[gid + 1];
  float acc[8];
#pragma unroll
  for (int j = 0; j < 8; ++j) acc[j] = 0.f;
  int e = lo_e;
  for (; e + 3 < hi_e; e += 4) {
    bf16x8 v0 = *(const bf16x8*)(xhi + (size_t)esrc[e] * 128 + l * 8);
    bf16x8 v1 = *(const bf16x8*)(xhi + (size_t)esrc[e + 1] * 128 + l * 8);
    bf16x8 v2 = *(const bf16x8*)(xhi + (size_t)esrc[e + 2] * 128 + l * 8);
    bf16x8 v3 = *(const bf16x8*)(xhi + (size_t)esrc[e + 3] * 128 + l * 8);
#pragma unroll
    for (int j = 0; j < 8; ++j)
      acc[j] += (bf2f(v0[j]) + bf2f(v1[j])) + (bf2f(v2[j]) + bf2f(v3[j]));
  }
  for (; e < hi_e; ++e) {
    bf16x8 v0 = *(const bf16x8*)(xhi + (size_t)esrc[e] * 128 + l * 8);
#pragma unroll
    for (int j = 0; j < 8; ++j) acc[j] += bf2f(v0[j]);
  }
  float inv = (hi_e > lo_e) ? 1.0f / (float)(hi_e - lo_e) : 0.0f;
  bf16x8 oh, ol;
#pragma unroll
  for (int j = 0; j < 8; ++j) {
    float v = acc[j] * inv;
    short hv = f2bf(v);
    oh[j] = hv;
    ol[j] = f2bf(v - bf2f(hv));
  }
  *(bf16x8*)(ahi + (size_t)gid * 128 + l * 8) = oh;
  *(bf16x8*)(alo + (size_t)gid * 128 + l * 8) = ol;
}

// layer2: 32 lanes/node; lane owns 8 of 256 feats. Reads h_hi only.
__global__ __launch_bounds__(256) void gather2_kernel(
    const short* __restrict__ hhi, const int* __restrict__ row_start,
    const int* __restrict__ esrc, short* __restrict__ ahi,
    short* __restrict__ alo, int N) {
  int gid = (int)(((long long)blockIdx.x * 256 + threadIdx.x) >> 5);
  int l = threadIdx.x & 31;
  if (gid >= N) return;
  int lo_e = row_start[gid], hi_e = row_start[gid + 1];
  float acc[8];
#pragma unroll
  for (int j = 0; j < 8; ++j) acc[j] = 0.f;
  int e = lo_e;
  for (; e + 3 < hi_e; e += 4) {
    bf16x8 v0 = *(const bf16x8*)(hhi + (size_t)esrc[e] * HIDC + l * 8);
    bf16x8 v1 = *(const bf16x8*)(hhi + (size_t)esrc[e + 1] * HIDC + l * 8);
    bf16x8 v2 = *(const bf16x8*)(hhi + (size_t)esrc[e + 2] * HIDC + l * 8);
    bf16x8 v3 = *(const bf16x8*)(hhi + (size_t)esrc[e + 3] * HIDC + l * 8);
#pragma unroll
    for (int j = 0; j < 8; ++j)
      acc[j] += (bf2f(v0[j]) + bf2f(v1[j])) + (bf2f(v2[j]) + bf2f(v3[j]));
  }
  for (; e < hi_e; ++e) {
    bf16x8 v0 = *(const bf16x8*)(hhi + (size_t)esrc[e] * HIDC + l * 8);
#pragma unroll
    for (int j = 0; j < 8; ++j) acc[j] += bf2f(v0[j]);
  }
  float inv = (hi_e > lo_e) ? 1.0f / (float)(hi_e - lo_e) : 0.0f;
  bf16x8 oh, ol;
#pragma unroll
  for (int j = 0; j < 8; ++j) {
    float v = acc[j] * inv;
    short hv = f2bf(v);
    oh[j] = hv;
    ol[j] = f2bf(v - bf2f(hv));
  }
  *(bf16x8*)(ahi + (size_t)gid * HIDC + l * 8) = oh;
  *(bf16x8*)(alo + (size_t)gid * HIDC + l * 8) = ol;
}

// ---------------- MFMA GEMM ----------------
// C[i,j] = (relu?)(sum_k A[i,k]Wl[k,j] + sum_k X[i,k]Wr[k,j] + bias[j])
// Virtual K = 2*K1. Tiles: BM=128, BN=128, BK=32. 4 waves, 64x64 per wave.
template <int K1, bool RELU, bool OUTBF>
__global__ __launch_bounds__(256) void mfma_gemm(
    const short* __restrict__ Ahi, const short* __restrict__ Alo,
    const short* __restrict__ Xhi, const short* __restrict__ Xlo,
    const short* __restrict__ WLhi, const short* __restrict__ WLlo,
    const short* __restrict__ WRhi, const short* __restrict__ WRlo,
    const float* __restrict__ bias, float* __restrict__ Cf,
    short* __restrict__ Chi, short* __restrict__ Clo, int M) {
  __shared__ __align__(16) short As_hi[128][40];
  __shared__ __align__(16) short As_lo[128][40];
  __shared__ __align__(16) short Bs_hi[128][40];
  __shared__ __align__(16) short Bs_lo[128][40];

  const int tid = threadIdx.x;
  const int lane = tid & 63;
  const int w = tid >> 6;
  const int brow = blockIdx.y * 128;
  const int bcol = blockIdx.x * 128;
  const int wr = (w >> 1) * 64;
  const int wc = (w & 1) * 64;

  // staging map: 2 threads/row, each stages 2x16B per plane
  const int srow = tid >> 1;
  const int koff = (tid & 1) * 16;  // in shorts

  int arow = brow + srow;
  if (arow >= M) arow = M - 1;  // clamp (real data; stores guarded)
  const int bn = bcol + srow;

  f32x4 acc[4][4];
#pragma unroll
  for (int m = 0; m < 4; ++m)
#pragma unroll
    for (int n = 0; n < 4; ++n) acc[m][n] = (f32x4){0.f, 0.f, 0.f, 0.f};

  for (int k0 = 0; k0 < 2 * K1; k0 += 32) {
    const bool left = k0 < K1;
    const int kk = left ? k0 : k0 - K1;
    const short* __restrict__ Aph = left ? Ahi : Xhi;
    const short* __restrict__ Apl = left ? Alo : Xlo;
    const short* __restrict__ Bph = left ? WLhi : WRhi;
    const short* __restrict__ Bpl = left ? WLlo : WRlo;

    // global loads first (overlap with previous compute)
    size_t abase = (size_t)arow * K1 + kk + koff;
    size_t bbase = (size_t)bn * K1 + kk + koff;
    bf16x8 ga0 = *(const bf16x8*)(Aph + abase);
    bf16x8 ga1 = *(const bf16x8*)(Aph + abase + 8);
    bf16x8 ga2 = *(const bf16x8*)(Apl + abase);
    bf16x8 ga3 = *(const bf16x8*)(Apl + abase + 8);
    bf16x8 gb0 = *(const bf16x8*)(Bph + bbase);
    bf16x8 gb1 = *(const bf16x8*)(Bph + bbase + 8);
    bf16x8 gb2 = *(const bf16x8*)(Bpl + bbase);
    bf16x8 gb3 = *(const bf16x8*)(Bpl + bbase + 8);

    __syncthreads();  // previous iteration's frag reads complete
    *(bf16x8*)&As_hi[srow][koff] = ga0;
    *(bf16x8*)&As_hi[srow][koff + 8] = ga1;
    *(bf16x8*)&As_lo[srow][koff] = ga2;
    *(bf16x8*)&As_lo[srow][koff + 8] = ga3;
    *(bf16x8*)&Bs_hi[srow][koff] = gb0;
    *(bf16x8*)&Bs_hi[srow][koff + 8] = gb1;
    *(bf16x8*)&Bs_lo[srow][koff] = gb2;
    *(bf16x8*)&Bs_lo[srow][koff + 8] = gb3;
    __syncthreads();

    const int fr = lane & 15;
    const int fk = (lane >> 4) * 8;
    bf16x8 ah[4], al[4], bh[4], bl[4];
#pragma unroll
    for (int m = 0; m < 4; ++m) {
      ah[m] = *(const bf16x8*)&As_hi[wr + m * 16 + fr][fk];
      al[m] = *(const bf16x8*)&As_lo[wr + m * 16 + fr][fk];
    }
#pragma unroll
    for (int n = 0; n < 4; ++n) {
      bh[n] = *(const bf16x8*)&Bs_hi[wc + n * 16 + fr][fk];
      bl[n] = *(const bf16x8*)&Bs_lo[wc + n * 16 + fr][fk];
    }
#pragma unroll
    for (int m = 0; m < 4; ++m)
#pragma unroll
      for (int n = 0; n < 4; ++n) {
        acc[m][n] = __builtin_amdgcn_mfma_f32_16x16x32_bf16(ah[m], bh[n],
                                                            acc[m][n], 0, 0, 0);
        acc[m][n] = __builtin_amdgcn_mfma_f32_16x16x32_bf16(ah[m], bl[n],
                                                            acc[m][n], 0, 0, 0);
        acc[m][n] = __builtin_amdgcn_mfma_f32_16x16x32_bf16(al[m], bh[n],
                                                            acc[m][n], 0, 0, 0);
      }
  }

  // epilogue: C/D layout col=lane&15, row=(lane>>4)*4+j  [m89/m91 verified]
  const int lcol = lane & 15;
  const int lrow = (lane >> 4) * 4;
#pragma unroll
  for (int m = 0; m < 4; ++m) {
    int gr0 = brow + wr + m * 16 + lrow;
#pragma unroll
    for (int n = 0; n < 4; ++n) {
      int gc = bcol + wc + n * 16 + lcol;
      float bv = bias[gc];
#pragma unroll
      for (int j = 0; j < 4; ++j) {
        int gr = gr0 + j;
        if (gr >= M) continue;
        float v = acc[m][n][j] + bv;
        if (RELU) v = fmaxf(v, 0.f);
        if (OUTBF) {
          short hv = f2bf(v);
          Chi[(size_t)gr * HIDC + gc] = hv;
          Clo[(size_t)gr * HIDC + gc] = f2bf(v - bf2f(hv));
        } else {
          Cf[(size_t)gr * HIDC + gc] = v;
        }
      }
    }
  }
}

extern "C" void kernel_launch(void* const* d_in, const int* in_sizes, int n_in,
                              void* d_out, int out_size, void* d_ws,
                              size_t ws_size, hipStream_t stream) {
  const float* x = (const float*)d_in[0];
  const int* ei = (const int*)d_in[1];
  const float* W1l = (const float*)d_in[2];
  const float* b1 = (const float*)d_in[3];
  const float* W1r = (const float*)d_in[4];
  const float* W2l = (const float*)d_in[5];
  const float* b2 = (const float*)d_in[6];
  const float* W2r = (const float*)d_in[7];
  float* out = (float*)d_out;

  const int N = in_sizes[0] / 128;  // 50000
  const int E = in_sizes[1] / 2;    // 800000
  const int* src = ei;
  const int* dst = ei + E;

  char* ws = (char*)d_ws;
  size_t off = 0;
  auto walloc = [&](size_t bytes) {
    void* p = ws + off;
    off += (bytes + 255) & ~(size_t)255;
    return p;
  };
  int* deg = (int*)walloc((size_t)N * 4);
  int* row_start = (int*)walloc((size_t)(N + 1) * 4);
  int* cursor = (int*)walloc((size_t)N * 4);
  int* esrc = (int*)walloc((size_t)E * 4);
  int* bsum = (int*)walloc(256 * 4);
  int* boff = (int*)walloc(256 * 4);
  short* x_hi = (short*)walloc((size_t)N * 128 * 2);
  short* x_lo = (short*)walloc((size_t)N * 128 * 2);
  short* agg1_hi = (short*)walloc((size_t)N * 128 * 2);
  short* agg1_lo = (short*)walloc((size_t)N * 128 * 2);
  short* h_hi = (short*)walloc((size_t)N * 256 * 2);
  short* h_lo = (short*)walloc((size_t)N * 256 * 2);
  short* agg2_hi = (short*)walloc((size_t)N * 256 * 2);
  short* agg2_lo = (short*)walloc((size_t)N * 256 * 2);
  short* Wt1l_hi = (short*)walloc(128 * 256 * 2);
  short* Wt1l_lo = (short*)walloc(128 * 256 * 2);
  short* Wt1r_hi = (short*)walloc(128 * 256 * 2);
  short* Wt1r_lo = (short*)walloc(128 * 256 * 2);
  short* Wt2l_hi = (short*)walloc(256 * 256 * 2);
  short* Wt2l_lo = (short*)walloc(256 * 256 * 2);
  short* Wt2r_hi = (short*)walloc(256 * 256 * 2);
  short* Wt2r_lo = (short*)walloc(256 * 256 * 2);
  (void)ws_size;
  (void)n_in;
  (void)out_size;

  const int BLK = 256;
  const int eblocks = (E + BLK - 1) / BLK;
  const int nblocks = (N + BLK - 1) / BLK;  // 196

  // conversions (independent of CSR)
  xconv_kernel<<<(N * 32 + BLK - 1) / BLK, BLK, 0, stream>>>(
      (const float4*)x, (s16x4*)x_hi, (s16x4*)x_lo, N * 32);
  wconv_kernel<128, 256><<<(128 * 256 + BLK - 1) / BLK, BLK, 0, stream>>>(
      W1l, Wt1l_hi, Wt1l_lo);
  wconv_kernel<128, 256><<<(128 * 256 + BLK - 1) / BLK, BLK, 0, stream>>>(
      W1r, Wt1r_hi, Wt1r_lo);
  wconv_kernel<256, 256><<<(256 * 256 + BLK - 1) / BLK, BLK, 0, stream>>>(
      W2l, Wt2l_hi, Wt2l_lo);
  wconv_kernel<256, 256><<<(256 * 256 + BLK - 1) / BLK, BLK, 0, stream>>>(
      W2r, Wt2r_hi, Wt2r_lo);

  // CSR build (3-phase parallel scan)
  hipMemsetAsync(deg, 0, (size_t)N * 4, stream);
  deg_count_kernel<<<eblocks, BLK, 0, stream>>>(dst, deg, E, N);
  blocksum_kernel<<<nblocks, BLK, 0, stream>>>(deg, bsum, N);
  bscan_kernel<<<1, 256, 0, stream>>>(bsum, boff, row_start, nblocks, N);
  scatter_offsets_kernel<<<nblocks, BLK, 0, stream>>>(deg, boff, row_start,
                                                      cursor, N);
  fill_kernel<<<eblocks, BLK, 0, stream>>>(src, dst, cursor, esrc, E, N);

  // layer 1 (gather reads x_hi -> must follow xconv)
  gather1_kernel<<<(N * 16 + BLK - 1) / BLK, BLK, 0, stream>>>(
      x_hi, row_start, esrc, agg1_hi, agg1_lo, N);
  {
    dim3 grid(2, (N + 127) / 128);
    mfma_gemm<128, true, true><<<grid, BLK, 0, stream>>>(
        agg1_hi, agg1_lo, x_hi, x_lo, Wt1l_hi, Wt1l_lo, Wt1r_hi, Wt1r_lo, b1,
        nullptr, h_hi, h_lo, N);
  }

  // layer 2
  gather2_kernel<<<(N * 32 + BLK - 1) / BLK, BLK, 0, stream>>>(
      h_hi, row_start, esrc, agg2_hi, agg2_lo, N);
  {
    dim3 grid(2, (N + 127) / 128);
    mfma_gemm<256, false, false><<<grid, BLK, 0, stream>>>(
        agg2_hi, agg2_lo, h_hi, h_lo, Wt2l_hi, Wt2l_lo, Wt2r_hi, Wt2r_lo, b2,
        out, nullptr, nullptr, N);
  }
}

// Round 6
// 407.314 us; speedup vs baseline: 1.8906x; 1.0313x over previous
//
#include <hip/hip_runtime.h>
#include <hip/hip_bf16.h>

// GraphSAGE 2-hop. CSR-gather aggregation + split-bf16 MFMA GEMMs.
// R5 change: GEMM was LDS-BW-bound (MfmaUtil 20%, 24KB LDS per 48-MFMA
// wave-kstep vs 128B/clk pipe). New shape: BM=128, BN=256 (full width),
// 4 waves, wave tile 128x64 (M_rep=8, N_rep=4) -> 96 MFMA per 24KB read,
// A staged/fetched once (was twice), XOR-swizzled LDS staging to kill the
// 4-way write bank conflicts. __launch_bounds__(256,2) caps VGPR at 256.

typedef __attribute__((ext_vector_type(8))) short bf16x8;
typedef __attribute__((ext_vector_type(4))) float f32x4;
typedef __attribute__((ext_vector_type(4))) short s16x4;

constexpr int HIDC = 256;

__device__ __forceinline__ short f2bf(float v) {
  __hip_bfloat16 h = __float2bfloat16(v);  // RNE
  return *reinterpret_cast<short*>(&h);
}
__device__ __forceinline__ float bf2f(short s) {
  unsigned int u = ((unsigned int)(unsigned short)s) << 16;
  float f;
  __builtin_memcpy(&f, &u, 4);
  return f;
}

// ---------------- CSR build ----------------
__global__ __launch_bounds__(256) void deg_count_kernel(
    const int* __restrict__ dst, int* __restrict__ deg, int E, int N) {
  int e = blockIdx.x * blockDim.x + threadIdx.x;
  if (e < E) {
    int d = dst[e];
    if ((unsigned)d < (unsigned)N) atomicAdd(&deg[d], 1);
  }
}

__global__ __launch_bounds__(256) void blocksum_kernel(
    const int* __restrict__ deg, int* __restrict__ bsum, int N) {
  __shared__ int red[256];
  int i = blockIdx.x * 256 + threadIdx.x;
  red[threadIdx.x] = (i < N) ? deg[i] : 0;
  __syncthreads();
#pragma unroll
  for (int off = 128; off > 0; off >>= 1) {
    if (threadIdx.x < off) red[threadIdx.x] += red[threadIdx.x + off];
    __syncthreads();
  }
  if (threadIdx.x == 0) bsum[blockIdx.x] = red[0];
}

__global__ __launch_bounds__(256) void bscan_kernel(
    const int* __restrict__ bsum, int* __restrict__ boff,
    int* __restrict__ row_start, int nb, int N) {
  __shared__ int s[256];
  int t = threadIdx.x;
  s[t] = (t < nb) ? bsum[t] : 0;
  __syncthreads();
  for (int off = 1; off < 256; off <<= 1) {
    int v = (t >= off) ? s[t - off] : 0;
    __syncthreads();
    s[t] += v;
    __syncthreads();
  }
  if (t < nb) boff[t] = (t == 0) ? 0 : s[t - 1];
  if (t == nb - 1) row_start[N] = s[t];
}

__global__ __launch_bounds__(256) void scatter_offsets_kernel(
    const int* __restrict__ deg, const int* __restrict__ boff,
    int* __restrict__ row_start, int* __restrict__ cursor, int N) {
  __shared__ int s[256];
  int i = blockIdx.x * 256 + threadIdx.x;
  int t = threadIdx.x;
  int v = (i < N) ? deg[i] : 0;
  s[t] = v;
  __syncthreads();
  for (int off = 1; off < 256; off <<= 1) {
    int u = (t >= off) ? s[t - off] : 0;
    __syncthreads();
    s[t] += u;
    __syncthreads();
  }
  if (i < N) {
    int excl = s[t] - v + boff[blockIdx.x];
    row_start[i] = excl;
    cursor[i] = excl;
  }
}

__global__ __launch_bounds__(256) void fill_kernel(
    const int* __restrict__ src, const int* __restrict__ dst,
    int* __restrict__ cursor, int* __restrict__ esrc, int E, int N) {
  int e = blockIdx.x * blockDim.x + threadIdx.x;
  if (e < E) {
    int d = dst[e];
    if ((unsigned)d < (unsigned)N) {
      int p = atomicAdd(&cursor[d], 1);
      esrc[p] = src[e];
    }
  }
}

// ---------------- conversions ----------------
__global__ __launch_bounds__(256) void xconv_kernel(
    const float4* __restrict__ x, s16x4* __restrict__ hi,
    s16x4* __restrict__ lo, int total4) {
  int i = blockIdx.x * 256 + threadIdx.x;
  if (i >= total4) return;
  float4 v = x[i];
  s16x4 h, l;
  h.x = f2bf(v.x); l.x = f2bf(v.x - bf2f(h.x));
  h.y = f2bf(v.y); l.y = f2bf(v.y - bf2f(h.y));
  h.z = f2bf(v.z); l.z = f2bf(v.z - bf2f(h.z));
  h.w = f2bf(v.w); l.w = f2bf(v.w - bf2f(h.w));
  hi[i] = h;
  lo[i] = l;
}

// W [K][NN] fp32 -> Wt planes [NN][K] bf16 hi/lo
template <int K, int NN>
__global__ __launch_bounds__(256) void wconv_kernel(
    const float* __restrict__ W, short* __restrict__ Wt_hi,
    short* __restrict__ Wt_lo) {
  int tid = blockIdx.x * 256 + threadIdx.x;
  if (tid >= K * NN) return;
  int k = tid / NN, n = tid % NN;
  float v = W[tid];
  short hv = f2bf(v);
  Wt_hi[n * K + k] = hv;
  Wt_lo[n * K + k] = f2bf(v - bf2f(hv));
}

// ---------------- gathers ----------------
// layer1: 16 lanes/node; lane owns 8 of 128 feats (16B). Reads x_hi only.
__global__ __launch_bounds__(256) void gather1_kernel(
    const short* __restrict__ xhi, const int* __restrict__ row_start,
    const int* __restrict__ esrc, short* __restrict__ ahi,
    short* __restrict__ alo, int N) {
  int gid = (int)(((long long)blockIdx.x * 256 + threadIdx.x) >> 4);
  int l = threadIdx.x & 15;
  if (gid >= N) return;
  int lo_e = row_start[gid], hi_e = row_start[gid + 1];
  float acc[8];
#pragma unroll
  for (int j = 0; j < 8; ++j) acc[j] = 0.f;
  int e = lo_e;
  for (; e + 3 < hi_e; e += 4) {
    bf16x8 v0 = *(const bf16x8*)(xhi + (size_t)esrc[e] * 128 + l * 8);
    bf16x8 v1 = *(const bf16x8*)(xhi + (size_t)esrc[e + 1] * 128 + l * 8);
    bf16x8 v2 = *(const bf16x8*)(xhi + (size_t)esrc[e + 2] * 128 + l * 8);
    bf16x8 v3 = *(const bf16x8*)(xhi + (size_t)esrc[e + 3] * 128 + l * 8);
#pragma unroll
    for (int j = 0; j < 8; ++j)
      acc[j] += (bf2f(v0[j]) + bf2f(v1[j])) + (bf2f(v2[j]) + bf2f(v3[j]));
  }
  for (; e < hi_e; ++e) {
    bf16x8 v0 = *(const bf16x8*)(xhi + (size_t)esrc[e] * 128 + l * 8);
#pragma unroll
    for (int j = 0; j < 8; ++j) acc[j] += bf2f(v0[j]);
  }
  float inv = (hi_e > lo_e) ? 1.0f / (float)(hi_e - lo_e) : 0.0f;
  bf16x8 oh, ol;
#pragma unroll
  for (int j = 0; j < 8; ++j) {
    float v = acc[j] * inv;
    short hv = f2bf(v);
    oh[j] = hv;
    ol[j] = f2bf(v - bf2f(hv));
  }
  *(bf16x8*)(ahi + (size_t)gid * 128 + l * 8) = oh;
  *(bf16x8*)(alo + (size_t)gid * 128 + l * 8) = ol;
}

// layer2: 32 lanes/node; lane owns 8 of 256 feats. Reads h_hi only.
__global__ __launch_bounds__(256) void gather2_kernel(
    const short* __restrict__ hhi, const int* __restrict__ row_start,
    const int* __restrict__ esrc, short* __restrict__ ahi,
    short* __restrict__ alo, int N) {
  int gid = (int)(((long long)blockIdx.x * 256 + threadIdx.x) >> 5);
  int l = threadIdx.x & 31;
  if (gid >= N) return;
  int lo_e = row_start[gid], hi_e = row_start[gid + 1];
  float acc[8];
#pragma unroll
  for (int j = 0; j < 8; ++j) acc[j] = 0.f;
  int e = lo_e;
  for (; e + 3 < hi_e; e += 4) {
    bf16x8 v0 = *(const bf16x8*)(hhi + (size_t)esrc[e] * HIDC + l * 8);
    bf16x8 v1 = *(const bf16x8*)(hhi + (size_t)esrc[e + 1] * HIDC + l * 8);
    bf16x8 v2 = *(const bf16x8*)(hhi + (size_t)esrc[e + 2] * HIDC + l * 8);
    bf16x8 v3 = *(const bf16x8*)(hhi + (size_t)esrc[e + 3] * HIDC + l * 8);
#pragma unroll
    for (int j = 0; j < 8; ++j)
      acc[j] += (bf2f(v0[j]) + bf2f(v1[j])) + (bf2f(v2[j]) + bf2f(v3[j]));
  }
  for (; e < hi_e; ++e) {
    bf16x8 v0 = *(const bf16x8*)(hhi + (size_t)esrc[e] * HIDC + l * 8);
#pragma unroll
    for (int j = 0; j < 8; ++j) acc[j] += bf2f(v0[j]);
  }
  float inv = (hi_e > lo_e) ? 1.0f / (float)(hi_e - lo_e) : 0.0f;
  bf16x8 oh, ol;
#pragma unroll
  for (int j = 0; j < 8; ++j) {
    float v = acc[j] * inv;
    short hv = f2bf(v);
    oh[j] = hv;
    ol[j] = f2bf(v - bf2f(hv));
  }
  *(bf16x8*)(ahi + (size_t)gid * HIDC + l * 8) = oh;
  *(bf16x8*)(alo + (size_t)gid * HIDC + l * 8) = ol;
}

// ---------------- MFMA GEMM ----------------
// C[i,j] = (relu?)(sum_k A[i,k]Wl[k,j] + sum_k X[i,k]Wr[k,j] + bias[j])
// Virtual K = 2*K1. BM=128, BN=256 (full width), BK=32, 4 waves.
// Wave tile 128x64: M_rep=8, N_rep=4 -> 96 MFMA / 24 ds_read_b128 per kstep.
// LDS rows: 40 shorts (80B); 16-short blocks XOR-swizzled by row parity so
// staging writes hit distinct banks (was 4-way conflicted).
#define SWZ(row, c) ((c) ^ (((row) & 1) << 4))

template <int K1, bool RELU, bool OUTBF>
__global__ __launch_bounds__(256, 2) void mfma_gemm(
    const short* __restrict__ Ahi, const short* __restrict__ Alo,
    const short* __restrict__ Xhi, const short* __restrict__ Xlo,
    const short* __restrict__ WLhi, const short* __restrict__ WLlo,
    const short* __restrict__ WRhi, const short* __restrict__ WRlo,
    const float* __restrict__ bias, float* __restrict__ Cf,
    short* __restrict__ Chi, short* __restrict__ Clo, int M) {
  __shared__ __align__(16) short As_hi[128][40];
  __shared__ __align__(16) short As_lo[128][40];
  __shared__ __align__(16) short Bs_hi[256][40];
  __shared__ __align__(16) short Bs_lo[256][40];

  const int tid = threadIdx.x;
  const int lane = tid & 63;
  const int w = tid >> 6;        // wave 0..3
  const int brow = blockIdx.x * 128;
  const int wc = w * 64;         // wave's 64-col slice of the 256 cols

  // staging map: 2 threads per row; thread covers 16 shorts [koff, koff+16)
  const int srow = tid >> 1;          // 0..127
  const int koff = (tid & 1) * 16;    // 0 or 16 (shorts)
  const int skoff = SWZ(srow, koff);  // same parity for srow and srow+128

  int arow = brow + srow;
  if (arow >= M) arow = M - 1;  // clamp (real data; stores guarded)

  f32x4 acc[8][4];
#pragma unroll
  for (int m = 0; m < 8; ++m)
#pragma unroll
    for (int n = 0; n < 4; ++n) acc[m][n] = (f32x4){0.f, 0.f, 0.f, 0.f};

  for (int k0 = 0; k0 < 2 * K1; k0 += 32) {
    const bool left = k0 < K1;
    const int kk = left ? k0 : k0 - K1;
    const short* __restrict__ Aph = left ? Ahi : Xhi;
    const short* __restrict__ Apl = left ? Alo : Xlo;
    const short* __restrict__ Bph = left ? WLhi : WRhi;
    const short* __restrict__ Bpl = left ? WLlo : WRlo;

    // global loads (A: 1 row-half x 2 planes; B: 2 row-halves x 2 planes)
    size_t abase = (size_t)arow * K1 + kk + koff;
    size_t bbase0 = (size_t)srow * K1 + kk + koff;
    size_t bbase1 = (size_t)(srow + 128) * K1 + kk + koff;
    bf16x8 gah0 = *(const bf16x8*)(Aph + abase);
    bf16x8 gah1 = *(const bf16x8*)(Aph + abase + 8);
    bf16x8 gal0 = *(const bf16x8*)(Apl + abase);
    bf16x8 gal1 = *(const bf16x8*)(Apl + abase + 8);
    bf16x8 gbh00 = *(const bf16x8*)(Bph + bbase0);
    bf16x8 gbh01 = *(const bf16x8*)(Bph + bbase0 + 8);
    bf16x8 gbh10 = *(const bf16x8*)(Bph + bbase1);
    bf16x8 gbh11 = *(const bf16x8*)(Bph + bbase1 + 8);
    bf16x8 gbl00 = *(const bf16x8*)(Bpl + bbase0);
    bf16x8 gbl01 = *(const bf16x8*)(Bpl + bbase0 + 8);
    bf16x8 gbl10 = *(const bf16x8*)(Bpl + bbase1);
    bf16x8 gbl11 = *(const bf16x8*)(Bpl + bbase1 + 8);

    __syncthreads();  // previous iteration's frag reads complete
    *(bf16x8*)&As_hi[srow][skoff] = gah0;
    *(bf16x8*)&As_hi[srow][skoff + 8] = gah1;
    *(bf16x8*)&As_lo[srow][skoff] = gal0;
    *(bf16x8*)&As_lo[srow][skoff + 8] = gal1;
    *(bf16x8*)&Bs_hi[srow][skoff] = gbh00;
    *(bf16x8*)&Bs_hi[srow][skoff + 8] = gbh01;
    *(bf16x8*)&Bs_hi[srow + 128][skoff] = gbh10;
    *(bf16x8*)&Bs_hi[srow + 128][skoff + 8] = gbh11;
    *(bf16x8*)&Bs_lo[srow][skoff] = gbl00;
    *(bf16x8*)&Bs_lo[srow][skoff + 8] = gbl01;
    *(bf16x8*)&Bs_lo[srow + 128][skoff] = gbl10;
    *(bf16x8*)&Bs_lo[srow + 128][skoff + 8] = gbl11;
    __syncthreads();

    const int fr = lane & 15;
    const int fk = (lane >> 4) * 8;  // 0,8,16,24 -> logical shorts 0..31
    // logical k-halves: fk<16 in block0, else block1; apply row-parity XOR
    bf16x8 bh[4], bl[4];
#pragma unroll
    for (int n = 0; n < 4; ++n) {
      int br = wc + n * 16 + fr;
      int fks = SWZ(br, fk);
      bh[n] = *(const bf16x8*)&Bs_hi[br][fks];
      bl[n] = *(const bf16x8*)&Bs_lo[br][fks];
    }
#pragma unroll
    for (int m = 0; m < 8; ++m) {
      int ar = m * 16 + fr;
      int fks = SWZ(ar, fk);
      bf16x8 ah = *(const bf16x8*)&As_hi[ar][fks];
      bf16x8 al = *(const bf16x8*)&As_lo[ar][fks];
#pragma unroll
      for (int n = 0; n < 4; ++n) {
        acc[m][n] = __builtin_amdgcn_mfma_f32_16x16x32_bf16(ah, bh[n],
                                                            acc[m][n], 0, 0, 0);
        acc[m][n] = __builtin_amdgcn_mfma_f32_16x16x32_bf16(ah, bl[n],
                                                            acc[m][n], 0, 0, 0);
        acc[m][n] = __builtin_amdgcn_mfma_f32_16x16x32_bf16(al, bh[n],
                                                            acc[m][n], 0, 0, 0);
      }
    }
  }

  // epilogue: C/D layout col=lane&15, row=(lane>>4)*4+j  [m89/m91 verified]
  const int lcol = lane & 15;
  const int lrow = (lane >> 4) * 4;
#pragma unroll
  for (int m = 0; m < 8; ++m) {
    int gr0 = brow + m * 16 + lrow;
#pragma unroll
    for (int n = 0; n < 4; ++n) {
      int gc = wc + n * 16 + lcol;
      float bv = bias[gc];
#pragma unroll
      for (int j = 0; j < 4; ++j) {
        int gr = gr0 + j;
        if (gr >= M) continue;
        float v = acc[m][n][j] + bv;
        if (RELU) v = fmaxf(v, 0.f);
        if (OUTBF) {
          short hv = f2bf(v);
          Chi[(size_t)gr * HIDC + gc] = hv;
          Clo[(size_t)gr * HIDC + gc] = f2bf(v - bf2f(hv));
        } else {
          Cf[(size_t)gr * HIDC + gc] = v;
        }
      }
    }
  }
}

extern "C" void kernel_launch(void* const* d_in, const int* in_sizes, int n_in,
                              void* d_out, int out_size, void* d_ws,
                              size_t ws_size, hipStream_t stream) {
  const float* x = (const float*)d_in[0];
  const int* ei = (const int*)d_in[1];
  const float* W1l = (const float*)d_in[2];
  const float* b1 = (const float*)d_in[3];
  const float* W1r = (const float*)d_in[4];
  const float* W2l = (const float*)d_in[5];
  const float* b2 = (const float*)d_in[6];
  const float* W2r = (const float*)d_in[7];
  float* out = (float*)d_out;

  const int N = in_sizes[0] / 128;  // 50000
  const int E = in_sizes[1] / 2;    // 800000
  const int* src = ei;
  const int* dst = ei + E;

  char* ws = (char*)d_ws;
  size_t off = 0;
  auto walloc = [&](size_t bytes) {
    void* p = ws + off;
    off += (bytes + 255) & ~(size_t)255;
    return p;
  };
  int* deg = (int*)walloc((size_t)N * 4);
  int* row_start = (int*)walloc((size_t)(N + 1) * 4);
  int* cursor = (int*)walloc((size_t)N * 4);
  int* esrc = (int*)walloc((size_t)E * 4);
  int* bsum = (int*)walloc(256 * 4);
  int* boff = (int*)walloc(256 * 4);
  short* x_hi = (short*)walloc((size_t)N * 128 * 2);
  short* x_lo = (short*)walloc((size_t)N * 128 * 2);
  short* agg1_hi = (short*)walloc((size_t)N * 128 * 2);
  short* agg1_lo = (short*)walloc((size_t)N * 128 * 2);
  short* h_hi = (short*)walloc((size_t)N * 256 * 2);
  short* h_lo = (short*)walloc((size_t)N * 256 * 2);
  short* agg2_hi = (short*)walloc((size_t)N * 256 * 2);
  short* agg2_lo = (short*)walloc((size_t)N * 256 * 2);
  short* Wt1l_hi = (short*)walloc(128 * 256 * 2);
  short* Wt1l_lo = (short*)walloc(128 * 256 * 2);
  short* Wt1r_hi = (short*)walloc(128 * 256 * 2);
  short* Wt1r_lo = (short*)walloc(128 * 256 * 2);
  short* Wt2l_hi = (short*)walloc(256 * 256 * 2);
  short* Wt2l_lo = (short*)walloc(256 * 256 * 2);
  short* Wt2r_hi = (short*)walloc(256 * 256 * 2);
  short* Wt2r_lo = (short*)walloc(256 * 256 * 2);
  (void)ws_size;
  (void)n_in;
  (void)out_size;

  const int BLK = 256;
  const int eblocks = (E + BLK - 1) / BLK;
  const int nblocks = (N + BLK - 1) / BLK;  // 196

  // conversions (independent of CSR)
  xconv_kernel<<<(N * 32 + BLK - 1) / BLK, BLK, 0, stream>>>(
      (const float4*)x, (s16x4*)x_hi, (s16x4*)x_lo, N * 32);
  wconv_kernel<128, 256><<<(128 * 256 + BLK - 1) / BLK, BLK, 0, stream>>>(
      W1l, Wt1l_hi, Wt1l_lo);
  wconv_kernel<128, 256><<<(128 * 256 + BLK - 1) / BLK, BLK, 0, stream>>>(
      W1r, Wt1r_hi, Wt1r_lo);
  wconv_kernel<256, 256><<<(256 * 256 + BLK - 1) / BLK, BLK, 0, stream>>>(
      W2l, Wt2l_hi, Wt2l_lo);
  wconv_kernel<256, 256><<<(256 * 256 + BLK - 1) / BLK, BLK, 0, stream>>>(
      W2r, Wt2r_hi, Wt2r_lo);

  // CSR build (3-phase parallel scan)
  hipMemsetAsync(deg, 0, (size_t)N * 4, stream);
  deg_count_kernel<<<eblocks, BLK, 0, stream>>>(dst, deg, E, N);
  blocksum_kernel<<<nblocks, BLK, 0, stream>>>(deg, bsum, N);
  bscan_kernel<<<1, 256, 0, stream>>>(bsum, boff, row_start, nblocks, N);
  scatter_offsets_kernel<<<nblocks, BLK, 0, stream>>>(deg, boff, row_start,
                                                      cursor, N);
  fill_kernel<<<eblocks, BLK, 0, stream>>>(src, dst, cursor, esrc, E, N);

  // layer 1
  gather1_kernel<<<(N * 16 + BLK - 1) / BLK, BLK, 0, stream>>>(
      x_hi, row_start, esrc, agg1_hi, agg1_lo, N);
  {
    dim3 grid((N + 127) / 128);
    mfma_gemm<128, true, true><<<grid, BLK, 0, stream>>>(
        agg1_hi, agg1_lo, x_hi, x_lo, Wt1l_hi, Wt1l_lo, Wt1r_hi, Wt1r_lo, b1,
        nullptr, h_hi, h_lo, N);
  }

  // layer 2
  gather2_kernel<<<(N * 32 + BLK - 1) / BLK, BLK, 0, stream>>>(
      h_hi, row_start, esrc, agg2_hi, agg2_lo, N);
  {
    dim3 grid((N + 127) / 128);
    mfma_gemm<256, false, false><<<grid, BLK, 0, stream>>>(
        agg2_hi, agg2_lo, h_hi, h_lo, Wt2l_hi, Wt2l_lo, Wt2r_hi, Wt2r_lo, b2,
        out, nullptr, nullptr, N);
  }
}

// Round 7
// 361.824 us; speedup vs baseline: 2.1283x; 1.1257x over previous
//
#include <hip/hip_runtime.h>
#include <hip/hip_bf16.h>

// GraphSAGE 2-hop. CSR-gather aggregation + split-bf16 MFMA GEMMs.
// R7: (a) CSR fill split into deg_rank (atomic returns rank) + fill2 (no
// atomics); (b) GEMM rebuilt on the m97 shape: BM=BN=128, 32KB LDS,
// global_load_lds(16B) staging with chunk swizzle c^=(row>>1)&3 (linear LDS
// dest + inverse-swizzled global source), 4 waves, launch_bounds(256,4) for
// ~4 blocks/CU of cross-block latency hiding.

typedef __attribute__((ext_vector_type(8))) short bf16x8;
typedef __attribute__((ext_vector_type(4))) float f32x4;
typedef __attribute__((ext_vector_type(4))) short s16x4;

constexpr int HIDC = 256;

__device__ __forceinline__ short f2bf(float v) {
  __hip_bfloat16 h = __float2bfloat16(v);  // RNE
  return *reinterpret_cast<short*>(&h);
}
__device__ __forceinline__ float bf2f(short s) {
  unsigned int u = ((unsigned int)(unsigned short)s) << 16;
  float f;
  __builtin_memcpy(&f, &u, 4);
  return f;
}

__device__ __forceinline__ void gll16(const short* g, short* l) {
  __builtin_amdgcn_global_load_lds(
      (const __attribute__((address_space(1))) unsigned int*)g,
      (__attribute__((address_space(3))) unsigned int*)l, 16, 0, 0);
}

// ---------------- CSR build ----------------
__global__ __launch_bounds__(256) void deg_rank_kernel(
    const int* __restrict__ dst, int* __restrict__ deg, int* __restrict__ rank,
    int E, int N) {
  int e = blockIdx.x * blockDim.x + threadIdx.x;
  if (e < E) {
    int d = dst[e];
    if ((unsigned)d < (unsigned)N) rank[e] = atomicAdd(&deg[d], 1);
  }
}

__global__ __launch_bounds__(256) void blocksum_kernel(
    const int* __restrict__ deg, int* __restrict__ bsum, int N) {
  __shared__ int red[256];
  int i = blockIdx.x * 256 + threadIdx.x;
  red[threadIdx.x] = (i < N) ? deg[i] : 0;
  __syncthreads();
#pragma unroll
  for (int off = 128; off > 0; off >>= 1) {
    if (threadIdx.x < off) red[threadIdx.x] += red[threadIdx.x + off];
    __syncthreads();
  }
  if (threadIdx.x == 0) bsum[blockIdx.x] = red[0];
}

__global__ __launch_bounds__(256) void bscan_kernel(
    const int* __restrict__ bsum, int* __restrict__ boff,
    int* __restrict__ row_start, int nb, int N) {
  __shared__ int s[256];
  int t = threadIdx.x;
  s[t] = (t < nb) ? bsum[t] : 0;
  __syncthreads();
  for (int off = 1; off < 256; off <<= 1) {
    int v = (t >= off) ? s[t - off] : 0;
    __syncthreads();
    s[t] += v;
    __syncthreads();
  }
  if (t < nb) boff[t] = (t == 0) ? 0 : s[t - 1];
  if (t == nb - 1) row_start[N] = s[t];
}

__global__ __launch_bounds__(256) void scatter_offsets_kernel(
    const int* __restrict__ deg, const int* __restrict__ boff,
    int* __restrict__ row_start, int N) {
  __shared__ int s[256];
  int i = blockIdx.x * 256 + threadIdx.x;
  int t = threadIdx.x;
  int v = (i < N) ? deg[i] : 0;
  s[t] = v;
  __syncthreads();
  for (int off = 1; off < 256; off <<= 1) {
    int u = (t >= off) ? s[t - off] : 0;
    __syncthreads();
    s[t] += u;
    __syncthreads();
  }
  if (i < N) row_start[i] = s[t] - v + boff[blockIdx.x];
}

// no atomics: pos = row_start[dst] + rank
__global__ __launch_bounds__(256) void fill2_kernel(
    const int* __restrict__ src, const int* __restrict__ dst,
    const int* __restrict__ rank, const int* __restrict__ row_start,
    int* __restrict__ esrc, int E, int N) {
  int e = blockIdx.x * blockDim.x + threadIdx.x;
  if (e < E) {
    int d = dst[e];
    if ((unsigned)d < (unsigned)N) esrc[row_start[d] + rank[e]] = src[e];
  }
}

// ---------------- conversions ----------------
__global__ __launch_bounds__(256) void xconv_kernel(
    const float4* __restrict__ x, s16x4* __restrict__ hi,
    s16x4* __restrict__ lo, int total4) {
  int i = blockIdx.x * 256 + threadIdx.x;
  if (i >= total4) return;
  float4 v = x[i];
  s16x4 h, l;
  h.x = f2bf(v.x); l.x = f2bf(v.x - bf2f(h.x));
  h.y = f2bf(v.y); l.y = f2bf(v.y - bf2f(h.y));
  h.z = f2bf(v.z); l.z = f2bf(v.z - bf2f(h.z));
  h.w = f2bf(v.w); l.w = f2bf(v.w - bf2f(h.w));
  hi[i] = h;
  lo[i] = l;
}

// W [K][NN] fp32 -> Wt planes [NN][K] bf16 hi/lo
template <int K, int NN>
__global__ __launch_bounds__(256) void wconv_kernel(
    const float* __restrict__ W, short* __restrict__ Wt_hi,
    short* __restrict__ Wt_lo) {
  int tid = blockIdx.x * 256 + threadIdx.x;
  if (tid >= K * NN) return;
  int k = tid / NN, n = tid % NN;
  float v = W[tid];
  short hv = f2bf(v);
  Wt_hi[n * K + k] = hv;
  Wt_lo[n * K + k] = f2bf(v - bf2f(hv));
}

// ---------------- gathers ----------------
// layer1: 16 lanes/node; lane owns 8 of 128 feats (16B). Reads x_hi only.
__global__ __launch_bounds__(256) void gather1_kernel(
    const short* __restrict__ xhi, const int* __restrict__ row_start,
    const int* __restrict__ esrc, short* __restrict__ ahi,
    short* __restrict__ alo, int N) {
  int gid = (int)(((long long)blockIdx.x * 256 + threadIdx.x) >> 4);
  int l = threadIdx.x & 15;
  if (gid >= N) return;
  int lo_e = row_start[gid], hi_e = row_start[gid + 1];
  float acc[8];
#pragma unroll
  for (int j = 0; j < 8; ++j) acc[j] = 0.f;
  int e = lo_e;
  for (; e + 3 < hi_e; e += 4) {
    bf16x8 v0 = *(const bf16x8*)(xhi + (size_t)esrc[e] * 128 + l * 8);
    bf16x8 v1 = *(const bf16x8*)(xhi + (size_t)esrc[e + 1] * 128 + l * 8);
    bf16x8 v2 = *(const bf16x8*)(xhi + (size_t)esrc[e + 2] * 128 + l * 8);
    bf16x8 v3 = *(const bf16x8*)(xhi + (size_t)esrc[e + 3] * 128 + l * 8);
#pragma unroll
    for (int j = 0; j < 8; ++j)
      acc[j] += (bf2f(v0[j]) + bf2f(v1[j])) + (bf2f(v2[j]) + bf2f(v3[j]));
  }
  for (; e < hi_e; ++e) {
    bf16x8 v0 = *(const bf16x8*)(xhi + (size_t)esrc[e] * 128 + l * 8);
#pragma unroll
    for (int j = 0; j < 8; ++j) acc[j] += bf2f(v0[j]);
  }
  float inv = (hi_e > lo_e) ? 1.0f / (float)(hi_e - lo_e) : 0.0f;
  bf16x8 oh, ol;
#pragma unroll
  for (int j = 0; j < 8; ++j) {
    float v = acc[j] * inv;
    short hv = f2bf(v);
    oh[j] = hv;
    ol[j] = f2bf(v - bf2f(hv));
  }
  *(bf16x8*)(ahi + (size_t)gid * 128 + l * 8) = oh;
  *(bf16x8*)(alo + (size_t)gid * 128 + l * 8) = ol;
}

// layer2: 32 lanes/node; lane owns 8 of 256 feats. Reads h_hi only.
__global__ __launch_bounds__(256) void gather2_kernel(
    const short* __restrict__ hhi, const int* __restrict__ row_start,
    const int* __restrict__ esrc, short* __restrict__ ahi,
    short* __restrict__ alo, int N) {
  int gid = (int)(((long long)blockIdx.x * 256 + threadIdx.x) >> 5);
  int l = threadIdx.x & 31;
  if (gid >= N) return;
  int lo_e = row_start[gid], hi_e = row_start[gid + 1];
  float acc[8];
#pragma unroll
  for (int j = 0; j < 8; ++j) acc[j] = 0.f;
  int e = lo_e;
  for (; e + 3 < hi_e; e += 4) {
    bf16x8 v0 = *(const bf16x8*)(hhi + (size_t)esrc[e] * HIDC + l * 8);
    bf16x8 v1 = *(const bf16x8*)(hhi + (size_t)esrc[e + 1] * HIDC + l * 8);
    bf16x8 v2 = *(const bf16x8*)(hhi + (size_t)esrc[e + 2] * HIDC + l * 8);
    bf16x8 v3 = *(const bf16x8*)(hhi + (size_t)esrc[e + 3] * HIDC + l * 8);
#pragma unroll
    for (int j = 0; j < 8; ++j)
      acc[j] += (bf2f(v0[j]) + bf2f(v1[j])) + (bf2f(v2[j]) + bf2f(v3[j]));
  }
  for (; e < hi_e; ++e) {
    bf16x8 v0 = *(const bf16x8*)(hhi + (size_t)esrc[e] * HIDC + l * 8);
#pragma unroll
    for (int j = 0; j < 8; ++j) acc[j] += bf2f(v0[j]);
  }
  float inv = (hi_e > lo_e) ? 1.0f / (float)(hi_e - lo_e) : 0.0f;
  bf16x8 oh, ol;
#pragma unroll
  for (int j = 0; j < 8; ++j) {
    float v = acc[j] * inv;
    short hv = f2bf(v);
    oh[j] = hv;
    ol[j] = f2bf(v - bf2f(hv));
  }
  *(bf16x8*)(ahi + (size_t)gid * HIDC + l * 8) = oh;
  *(bf16x8*)(alo + (size_t)gid * HIDC + l * 8) = ol;
}

// ---------------- MFMA GEMM (m97 shape) ----------------
// C[i,j] = (relu?)(sum_k A[i,k]Wl[k,j] + sum_k X[i,k]Wr[k,j] + bias[j])
// Virtual K = 2*K1. BM=BN=128, BK=32, 4 waves (2x2), wave tile 64x64.
// LDS [row][32 shorts] linear 64B rows; 16B chunk swizzle c ^= (row>>1)&3
// applied on the GLOBAL source (stage) and on frag reads -> conflict-free.
template <int K1, bool RELU, bool OUTBF>
__global__ __launch_bounds__(256, 4) void mfma_gemm(
    const short* __restrict__ Ahi, const short* __restrict__ Alo,
    const short* __restrict__ Xhi, const short* __restrict__ Xlo,
    const short* __restrict__ WLhi, const short* __restrict__ WLlo,
    const short* __restrict__ WRhi, const short* __restrict__ WRlo,
    const float* __restrict__ bias, float* __restrict__ Cf,
    short* __restrict__ Chi, short* __restrict__ Clo, int M) {
  __shared__ __align__(16) short As_hi[128][32];
  __shared__ __align__(16) short As_lo[128][32];
  __shared__ __align__(16) short Bs_hi[128][32];
  __shared__ __align__(16) short Bs_lo[128][32];

  const int tid = threadIdx.x;
  const int lane = tid & 63;
  const int w = tid >> 6;  // 0..3
  const int brow = blockIdx.x * 128;
  const int bcol = blockIdx.y * 128;
  const int wrl = (w >> 1) * 64;  // wave row offset in tile
  const int wcl = (w & 1) * 64;   // wave col offset in tile

  // ---- staging geometry: wave w stages rows [16w,16w+16) and [64+16w,..)
  // of each plane. One global_load_lds(16B) covers 16 rows x 64B.
  const int lrow = lane >> 2;  // 0..15
  const int lc = lane & 3;     // 16B chunk within row
  const int r1 = 16 * w + lrow;
  const int r2 = 64 + 16 * w + lrow;
  const int ga1 = min(brow + r1, M - 1);
  const int ga2 = min(brow + r2, M - 1);
  // swizzle uses the LDS row; involution c_g = c_store ^ ((row>>1)&3)
  const int sw1 = (lc ^ ((r1 >> 1) & 3)) << 3;  // shorts
  const int sw2 = (lc ^ ((r2 >> 1) & 3)) << 3;
  const size_t aoff1 = (size_t)ga1 * K1 + sw1;
  const size_t aoff2 = (size_t)ga2 * K1 + sw2;
  const size_t boff1 = (size_t)(bcol + r1) * K1 + sw1;
  const size_t boff2 = (size_t)(bcol + r2) * K1 + sw2;
  short* const lAh1 = &As_hi[16 * w][0];
  short* const lAh2 = &As_hi[64 + 16 * w][0];
  short* const lAl1 = &As_lo[16 * w][0];
  short* const lAl2 = &As_lo[64 + 16 * w][0];
  short* const lBh1 = &Bs_hi[16 * w][0];
  short* const lBh2 = &Bs_hi[64 + 16 * w][0];
  short* const lBl1 = &Bs_lo[16 * w][0];
  short* const lBl2 = &Bs_lo[64 + 16 * w][0];

  f32x4 acc[4][4];
#pragma unroll
  for (int m = 0; m < 4; ++m)
#pragma unroll
    for (int n = 0; n < 4; ++n) acc[m][n] = (f32x4){0.f, 0.f, 0.f, 0.f};

  const int fr = lane & 15;
  const int q = lane >> 4;

  for (int k0 = 0; k0 < 2 * K1; k0 += 32) {
    const bool left = k0 < K1;
    const int kk = left ? k0 : k0 - K1;
    const short* __restrict__ Aph = left ? Ahi : Xhi;
    const short* __restrict__ Apl = left ? Alo : Xlo;
    const short* __restrict__ Bph = left ? WLhi : WRhi;
    const short* __restrict__ Bpl = left ? WLlo : WRlo;

    __syncthreads();  // all waves done reading previous tile
    gll16(Aph + aoff1 + kk, lAh1);
    gll16(Aph + aoff2 + kk, lAh2);
    gll16(Apl + aoff1 + kk, lAl1);
    gll16(Apl + aoff2 + kk, lAl2);
    gll16(Bph + boff1 + kk, lBh1);
    gll16(Bph + boff2 + kk, lBh2);
    gll16(Bpl + boff1 + kk, lBl1);
    gll16(Bpl + boff2 + kk, lBl2);
    __syncthreads();  // vmcnt drained -> LDS tile ready

    bf16x8 bh[4], bl[4];
#pragma unroll
    for (int n = 0; n < 4; ++n) {
      int r = wcl + n * 16 + fr;
      int off = r * 32 + ((q ^ ((r >> 1) & 3)) << 3);
      bh[n] = *(const bf16x8*)(&Bs_hi[0][0] + off);
      bl[n] = *(const bf16x8*)(&Bs_lo[0][0] + off);
    }
#pragma unroll
    for (int m = 0; m < 4; ++m) {
      int r = wrl + m * 16 + fr;
      int off = r * 32 + ((q ^ ((r >> 1) & 3)) << 3);
      bf16x8 ah = *(const bf16x8*)(&As_hi[0][0] + off);
      bf16x8 al = *(const bf16x8*)(&As_lo[0][0] + off);
#pragma unroll
      for (int n = 0; n < 4; ++n) {
        acc[m][n] = __builtin_amdgcn_mfma_f32_16x16x32_bf16(ah, bh[n],
                                                            acc[m][n], 0, 0, 0);
        acc[m][n] = __builtin_amdgcn_mfma_f32_16x16x32_bf16(ah, bl[n],
                                                            acc[m][n], 0, 0, 0);
        acc[m][n] = __builtin_amdgcn_mfma_f32_16x16x32_bf16(al, bh[n],
                                                            acc[m][n], 0, 0, 0);
      }
    }
  }

  // epilogue: C/D layout col=lane&15, row=(lane>>4)*4+j  [m89/m91 verified]
  const int lcol = lane & 15;
  const int lrw = (lane >> 4) * 4;
#pragma unroll
  for (int m = 0; m < 4; ++m) {
    int gr0 = brow + wrl + m * 16 + lrw;
#pragma unroll
    for (int n = 0; n < 4; ++n) {
      int gc = bcol + wcl + n * 16 + lcol;
      float bv = bias[gc];
#pragma unroll
      for (int j = 0; j < 4; ++j) {
        int gr = gr0 + j;
        if (gr >= M) continue;
        float v = acc[m][n][j] + bv;
        if (RELU) v = fmaxf(v, 0.f);
        if (OUTBF) {
          short hv = f2bf(v);
          Chi[(size_t)gr * HIDC + gc] = hv;
          Clo[(size_t)gr * HIDC + gc] = f2bf(v - bf2f(hv));
        } else {
          Cf[(size_t)gr * HIDC + gc] = v;
        }
      }
    }
  }
}

extern "C" void kernel_launch(void* const* d_in, const int* in_sizes, int n_in,
                              void* d_out, int out_size, void* d_ws,
                              size_t ws_size, hipStream_t stream) {
  const float* x = (const float*)d_in[0];
  const int* ei = (const int*)d_in[1];
  const float* W1l = (const float*)d_in[2];
  const float* b1 = (const float*)d_in[3];
  const float* W1r = (const float*)d_in[4];
  const float* W2l = (const float*)d_in[5];
  const float* b2 = (const float*)d_in[6];
  const float* W2r = (const float*)d_in[7];
  float* out = (float*)d_out;

  const int N = in_sizes[0] / 128;  // 50000
  const int E = in_sizes[1] / 2;    // 800000
  const int* src = ei;
  const int* dst = ei + E;

  char* ws = (char*)d_ws;
  size_t off = 0;
  auto walloc = [&](size_t bytes) {
    void* p = ws + off;
    off += (bytes + 255) & ~(size_t)255;
    return p;
  };
  int* deg = (int*)walloc((size_t)N * 4);
  int* row_start = (int*)walloc((size_t)(N + 1) * 4);
  int* rank = (int*)walloc((size_t)E * 4);
  int* esrc = (int*)walloc((size_t)E * 4);
  int* bsum = (int*)walloc(256 * 4);
  int* boff = (int*)walloc(256 * 4);
  short* x_hi = (short*)walloc((size_t)N * 128 * 2);
  short* x_lo = (short*)walloc((size_t)N * 128 * 2);
  short* agg1_hi = (short*)walloc((size_t)N * 128 * 2);
  short* agg1_lo = (short*)walloc((size_t)N * 128 * 2);
  short* h_hi = (short*)walloc((size_t)N * 256 * 2);
  short* h_lo = (short*)walloc((size_t)N * 256 * 2);
  short* agg2_hi = (short*)walloc((size_t)N * 256 * 2);
  short* agg2_lo = (short*)walloc((size_t)N * 256 * 2);
  short* Wt1l_hi = (short*)walloc(128 * 256 * 2);
  short* Wt1l_lo = (short*)walloc(128 * 256 * 2);
  short* Wt1r_hi = (short*)walloc(128 * 256 * 2);
  short* Wt1r_lo = (short*)walloc(128 * 256 * 2);
  short* Wt2l_hi = (short*)walloc(256 * 256 * 2);
  short* Wt2l_lo = (short*)walloc(256 * 256 * 2);
  short* Wt2r_hi = (short*)walloc(256 * 256 * 2);
  short* Wt2r_lo = (short*)walloc(256 * 256 * 2);
  (void)ws_size;
  (void)n_in;
  (void)out_size;

  const int BLK = 256;
  const int eblocks = (E + BLK - 1) / BLK;
  const int nblocks = (N + BLK - 1) / BLK;  // 196

  // conversions (independent of CSR)
  xconv_kernel<<<(N * 32 + BLK - 1) / BLK, BLK, 0, stream>>>(
      (const float4*)x, (s16x4*)x_hi, (s16x4*)x_lo, N * 32);
  wconv_kernel<128, 256><<<(128 * 256 + BLK - 1) / BLK, BLK, 0, stream>>>(
      W1l, Wt1l_hi, Wt1l_lo);
  wconv_kernel<128, 256><<<(128 * 256 + BLK - 1) / BLK, BLK, 0, stream>>>(
      W1r, Wt1r_hi, Wt1r_lo);
  wconv_kernel<256, 256><<<(256 * 256 + BLK - 1) / BLK, BLK, 0, stream>>>(
      W2l, Wt2l_hi, Wt2l_lo);
  wconv_kernel<256, 256><<<(256 * 256 + BLK - 1) / BLK, BLK, 0, stream>>>(
      W2r, Wt2r_hi, Wt2r_lo);

  // CSR build: one atomic pass (rank) + parallel scan + non-atomic fill
  hipMemsetAsync(deg, 0, (size_t)N * 4, stream);
  deg_rank_kernel<<<eblocks, BLK, 0, stream>>>(dst, deg, rank, E, N);
  blocksum_kernel<<<nblocks, BLK, 0, stream>>>(deg, bsum, N);
  bscan_kernel<<<1, 256, 0, stream>>>(bsum, boff, row_start, nblocks, N);
  scatter_offsets_kernel<<<nblocks, BLK, 0, stream>>>(deg, boff, row_start, N);
  fill2_kernel<<<eblocks, BLK, 0, stream>>>(src, dst, rank, row_start, esrc, E,
                                            N);

  // layer 1
  gather1_kernel<<<(N * 16 + BLK - 1) / BLK, BLK, 0, stream>>>(
      x_hi, row_start, esrc, agg1_hi, agg1_lo, N);
  {
    dim3 grid((N + 127) / 128, 2);
    mfma_gemm<128, true, true><<<grid, BLK, 0, stream>>>(
        agg1_hi, agg1_lo, x_hi, x_lo, Wt1l_hi, Wt1l_lo, Wt1r_hi, Wt1r_lo, b1,
        nullptr, h_hi, h_lo, N);
  }

  // layer 2
  gather2_kernel<<<(N * 32 + BLK - 1) / BLK, BLK, 0, stream>>>(
      h_hi, row_start, esrc, agg2_hi, agg2_lo, N);
  {
    dim3 grid((N + 127) / 128, 2);
    mfma_gemm<256, false, false><<<grid, BLK, 0, stream>>>(
        agg2_hi, agg2_lo, h_hi, h_lo, Wt2l_hi, Wt2l_lo, Wt2r_hi, Wt2r_lo, b2,
        out, nullptr, nullptr, N);
  }
}

// Round 8
// 346.951 us; speedup vs baseline: 2.2195x; 1.0429x over previous
//
#include <hip/hip_runtime.h>
#include <hip/hip_bf16.h>

// GraphSAGE 2-hop. CSR-gather aggregation + split-bf16 MFMA GEMMs.
// R8: GEMM wave tile 64x64 -> 128x64 (BM=256,BN=128, 4 waves 2x2): halves
// LDS frag-read cost per MFMA (was the R7 ceiling). XCD pairing swizzle puts
// the two bcol-blocks sharing an A-stripe on the same XCD L2.

typedef __attribute__((ext_vector_type(8))) short bf16x8;
typedef __attribute__((ext_vector_type(4))) float f32x4;
typedef __attribute__((ext_vector_type(4))) short s16x4;

constexpr int HIDC = 256;

__device__ __forceinline__ short f2bf(float v) {
  __hip_bfloat16 h = __float2bfloat16(v);  // RNE
  return *reinterpret_cast<short*>(&h);
}
__device__ __forceinline__ float bf2f(short s) {
  unsigned int u = ((unsigned int)(unsigned short)s) << 16;
  float f;
  __builtin_memcpy(&f, &u, 4);
  return f;
}

__device__ __forceinline__ void gll16(const short* g, short* l) {
  __builtin_amdgcn_global_load_lds(
      (const __attribute__((address_space(1))) unsigned int*)g,
      (__attribute__((address_space(3))) unsigned int*)l, 16, 0, 0);
}

// ---------------- CSR build ----------------
__global__ __launch_bounds__(256) void deg_rank_kernel(
    const int* __restrict__ dst, int* __restrict__ deg, int* __restrict__ rank,
    int E, int N) {
  int e = blockIdx.x * blockDim.x + threadIdx.x;
  if (e < E) {
    int d = dst[e];
    if ((unsigned)d < (unsigned)N) rank[e] = atomicAdd(&deg[d], 1);
  }
}

__global__ __launch_bounds__(256) void blocksum_kernel(
    const int* __restrict__ deg, int* __restrict__ bsum, int N) {
  __shared__ int red[256];
  int i = blockIdx.x * 256 + threadIdx.x;
  red[threadIdx.x] = (i < N) ? deg[i] : 0;
  __syncthreads();
#pragma unroll
  for (int off = 128; off > 0; off >>= 1) {
    if (threadIdx.x < off) red[threadIdx.x] += red[threadIdx.x + off];
    __syncthreads();
  }
  if (threadIdx.x == 0) bsum[blockIdx.x] = red[0];
}

__global__ __launch_bounds__(256) void bscan_kernel(
    const int* __restrict__ bsum, int* __restrict__ boff,
    int* __restrict__ row_start, int nb, int N) {
  __shared__ int s[256];
  int t = threadIdx.x;
  s[t] = (t < nb) ? bsum[t] : 0;
  __syncthreads();
  for (int off = 1; off < 256; off <<= 1) {
    int v = (t >= off) ? s[t - off] : 0;
    __syncthreads();
    s[t] += v;
    __syncthreads();
  }
  if (t < nb) boff[t] = (t == 0) ? 0 : s[t - 1];
  if (t == nb - 1) row_start[N] = s[t];
}

__global__ __launch_bounds__(256) void scatter_offsets_kernel(
    const int* __restrict__ deg, const int* __restrict__ boff,
    int* __restrict__ row_start, int N) {
  __shared__ int s[256];
  int i = blockIdx.x * 256 + threadIdx.x;
  int t = threadIdx.x;
  int v = (i < N) ? deg[i] : 0;
  s[t] = v;
  __syncthreads();
  for (int off = 1; off < 256; off <<= 1) {
    int u = (t >= off) ? s[t - off] : 0;
    __syncthreads();
    s[t] += u;
    __syncthreads();
  }
  if (i < N) row_start[i] = s[t] - v + boff[blockIdx.x];
}

// no atomics: pos = row_start[dst] + rank
__global__ __launch_bounds__(256) void fill2_kernel(
    const int* __restrict__ src, const int* __restrict__ dst,
    const int* __restrict__ rank, const int* __restrict__ row_start,
    int* __restrict__ esrc, int E, int N) {
  int e = blockIdx.x * blockDim.x + threadIdx.x;
  if (e < E) {
    int d = dst[e];
    if ((unsigned)d < (unsigned)N) esrc[row_start[d] + rank[e]] = src[e];
  }
}

// ---------------- conversions ----------------
__global__ __launch_bounds__(256) void xconv_kernel(
    const float4* __restrict__ x, s16x4* __restrict__ hi,
    s16x4* __restrict__ lo, int total4) {
  int i = blockIdx.x * 256 + threadIdx.x;
  if (i >= total4) return;
  float4 v = x[i];
  s16x4 h, l;
  h.x = f2bf(v.x); l.x = f2bf(v.x - bf2f(h.x));
  h.y = f2bf(v.y); l.y = f2bf(v.y - bf2f(h.y));
  h.z = f2bf(v.z); l.z = f2bf(v.z - bf2f(h.z));
  h.w = f2bf(v.w); l.w = f2bf(v.w - bf2f(h.w));
  hi[i] = h;
  lo[i] = l;
}

// W [K][NN] fp32 -> Wt planes [NN][K] bf16 hi/lo
template <int K, int NN>
__global__ __launch_bounds__(256) void wconv_kernel(
    const float* __restrict__ W, short* __restrict__ Wt_hi,
    short* __restrict__ Wt_lo) {
  int tid = blockIdx.x * 256 + threadIdx.x;
  if (tid >= K * NN) return;
  int k = tid / NN, n = tid % NN;
  float v = W[tid];
  short hv = f2bf(v);
  Wt_hi[n * K + k] = hv;
  Wt_lo[n * K + k] = f2bf(v - bf2f(hv));
}

// ---------------- gathers ----------------
// layer1: 16 lanes/node; lane owns 8 of 128 feats (16B). Reads x_hi only.
__global__ __launch_bounds__(256) void gather1_kernel(
    const short* __restrict__ xhi, const int* __restrict__ row_start,
    const int* __restrict__ esrc, short* __restrict__ ahi,
    short* __restrict__ alo, int N) {
  int gid = (int)(((long long)blockIdx.x * 256 + threadIdx.x) >> 4);
  int l = threadIdx.x & 15;
  if (gid >= N) return;
  int lo_e = row_start[gid], hi_e = row_start[gid + 1];
  float acc[8];
#pragma unroll
  for (int j = 0; j < 8; ++j) acc[j] = 0.f;
  int e = lo_e;
  for (; e + 3 < hi_e; e += 4) {
    bf16x8 v0 = *(const bf16x8*)(xhi + (size_t)esrc[e] * 128 + l * 8);
    bf16x8 v1 = *(const bf16x8*)(xhi + (size_t)esrc[e + 1] * 128 + l * 8);
    bf16x8 v2 = *(const bf16x8*)(xhi + (size_t)esrc[e + 2] * 128 + l * 8);
    bf16x8 v3 = *(const bf16x8*)(xhi + (size_t)esrc[e + 3] * 128 + l * 8);
#pragma unroll
    for (int j = 0; j < 8; ++j)
      acc[j] += (bf2f(v0[j]) + bf2f(v1[j])) + (bf2f(v2[j]) + bf2f(v3[j]));
  }
  for (; e < hi_e; ++e) {
    bf16x8 v0 = *(const bf16x8*)(xhi + (size_t)esrc[e] * 128 + l * 8);
#pragma unroll
    for (int j = 0; j < 8; ++j) acc[j] += bf2f(v0[j]);
  }
  float inv = (hi_e > lo_e) ? 1.0f / (float)(hi_e - lo_e) : 0.0f;
  bf16x8 oh, ol;
#pragma unroll
  for (int j = 0; j < 8; ++j) {
    float v = acc[j] * inv;
    short hv = f2bf(v);
    oh[j] = hv;
    ol[j] = f2bf(v - bf2f(hv));
  }
  *(bf16x8*)(ahi + (size_t)gid * 128 + l * 8) = oh;
  *(bf16x8*)(alo + (size_t)gid * 128 + l * 8) = ol;
}

// layer2: 32 lanes/node; lane owns 8 of 256 feats. Reads h_hi only.
__global__ __launch_bounds__(256) void gather2_kernel(
    const short* __restrict__ hhi, const int* __restrict__ row_start,
    const int* __restrict__ esrc, short* __restrict__ ahi,
    short* __restrict__ alo, int N) {
  int gid = (int)(((long long)blockIdx.x * 256 + threadIdx.x) >> 5);
  int l = threadIdx.x & 31;
  if (gid >= N) return;
  int lo_e = row_start[gid], hi_e = row_start[gid + 1];
  float acc[8];
#pragma unroll
  for (int j = 0; j < 8; ++j) acc[j] = 0.f;
  int e = lo_e;
  for (; e + 3 < hi_e; e += 4) {
    bf16x8 v0 = *(const bf16x8*)(hhi + (size_t)esrc[e] * HIDC + l * 8);
    bf16x8 v1 = *(const bf16x8*)(hhi + (size_t)esrc[e + 1] * HIDC + l * 8);
    bf16x8 v2 = *(const bf16x8*)(hhi + (size_t)esrc[e + 2] * HIDC + l * 8);
    bf16x8 v3 = *(const bf16x8*)(hhi + (size_t)esrc[e + 3] * HIDC + l * 8);
#pragma unroll
    for (int j = 0; j < 8; ++j)
      acc[j] += (bf2f(v0[j]) + bf2f(v1[j])) + (bf2f(v2[j]) + bf2f(v3[j]));
  }
  for (; e < hi_e; ++e) {
    bf16x8 v0 = *(const bf16x8*)(hhi + (size_t)esrc[e] * HIDC + l * 8);
#pragma unroll
    for (int j = 0; j < 8; ++j) acc[j] += bf2f(v0[j]);
  }
  float inv = (hi_e > lo_e) ? 1.0f / (float)(hi_e - lo_e) : 0.0f;
  bf16x8 oh, ol;
#pragma unroll
  for (int j = 0; j < 8; ++j) {
    float v = acc[j] * inv;
    short hv = f2bf(v);
    oh[j] = hv;
    ol[j] = f2bf(v - bf2f(hv));
  }
  *(bf16x8*)(ahi + (size_t)gid * HIDC + l * 8) = oh;
  *(bf16x8*)(alo + (size_t)gid * HIDC + l * 8) = ol;
}

// ---------------- MFMA GEMM ----------------
// C[i,j] = (relu?)(sum_k A[i,k]Wl[k,j] + sum_k X[i,k]Wr[k,j] + bias[j])
// Virtual K = 2*K1. BM=256, BN=128, BK=32, 4 waves (2Mx2N), wave tile 128x64
// (Mrep=8, Nrep=4, acc=128 VGPR). LDS 48KB linear rows of 32 shorts; 16B
// chunk swizzle c ^= (row>>1)&3 on global source + frag reads (R7-verified,
// 0 conflicts). Grid 1D 400: p = 8*(g>>4)+(g&7) (brow), bcol=(g>>3)&1 ->
// A-stripe pair lands on the same XCD (ids differ by 8).
template <int K1, bool RELU, bool OUTBF>
__global__ __launch_bounds__(256, 2) void mfma_gemm(
    const short* __restrict__ Ahi, const short* __restrict__ Alo,
    const short* __restrict__ Xhi, const short* __restrict__ Xlo,
    const short* __restrict__ WLhi, const short* __restrict__ WLlo,
    const short* __restrict__ WRhi, const short* __restrict__ WRlo,
    const float* __restrict__ bias, float* __restrict__ Cf,
    short* __restrict__ Chi, short* __restrict__ Clo, int M) {
  __shared__ __align__(16) short As_hi[256][32];
  __shared__ __align__(16) short As_lo[256][32];
  __shared__ __align__(16) short Bs_hi[128][32];
  __shared__ __align__(16) short Bs_lo[128][32];

  const int g = blockIdx.x;
  const int p = 8 * (g >> 4) + (g & 7);  // brow block 0..199
  const int bcolb = (g >> 3) & 1;        // 0 or 1
  if (p >= 196) return;                  // uniform per block: safe early exit
  const int brow = p * 256;
  const int bcol = bcolb * 128;

  const int tid = threadIdx.x;
  const int lane = tid & 63;
  const int w = tid >> 6;          // 0..3
  const int wrl = (w >> 1) * 128;  // wave row offset (0 or 128)
  const int wcl = (w & 1) * 64;    // wave col offset (0 or 64)

  // staging geometry: per pass, wave w covers LDS rows [p*64+16w, +16),
  // lane>>2 = row within 16, lane&3 = 16B chunk. Source chunk is swizzled.
  const int lrow = lane >> 2;
  const int lc = lane & 3;
  size_t aoff[4];
  size_t boff[2];
#pragma unroll
  for (int pp = 0; pp < 4; ++pp) {
    int r = pp * 64 + 16 * w + lrow;
    int gr = min(brow + r, M - 1);
    aoff[pp] = (size_t)gr * K1 + ((lc ^ ((r >> 1) & 3)) << 3);
  }
#pragma unroll
  for (int pp = 0; pp < 2; ++pp) {
    int r = pp * 64 + 16 * w + lrow;
    boff[pp] = (size_t)(bcol + r) * K1 + ((lc ^ ((r >> 1) & 3)) << 3);
  }

  f32x4 acc[8][4];
#pragma unroll
  for (int m = 0; m < 8; ++m)
#pragma unroll
    for (int n = 0; n < 4; ++n) acc[m][n] = (f32x4){0.f, 0.f, 0.f, 0.f};

  const int fr = lane & 15;
  const int q = lane >> 4;

  for (int k0 = 0; k0 < 2 * K1; k0 += 32) {
    const bool left = k0 < K1;
    const int kk = left ? k0 : k0 - K1;
    const short* __restrict__ Aph = left ? Ahi : Xhi;
    const short* __restrict__ Apl = left ? Alo : Xlo;
    const short* __restrict__ Bph = left ? WLhi : WRhi;
    const short* __restrict__ Bpl = left ? WLlo : WRlo;

    __syncthreads();  // all waves done reading previous tile
#pragma unroll
    for (int pp = 0; pp < 4; ++pp) {
      gll16(Aph + aoff[pp] + kk, &As_hi[pp * 64 + 16 * w][0]);
      gll16(Apl + aoff[pp] + kk, &As_lo[pp * 64 + 16 * w][0]);
    }
#pragma unroll
    for (int pp = 0; pp < 2; ++pp) {
      gll16(Bph + boff[pp] + kk, &Bs_hi[pp * 64 + 16 * w][0]);
      gll16(Bpl + boff[pp] + kk, &Bs_lo[pp * 64 + 16 * w][0]);
    }
    __syncthreads();  // vmcnt drained -> LDS tile ready

    bf16x8 bh[4], bl[4];
#pragma unroll
    for (int n = 0; n < 4; ++n) {
      int r = wcl + n * 16 + fr;
      int off = r * 32 + ((q ^ ((r >> 1) & 3)) << 3);
      bh[n] = *(const bf16x8*)(&Bs_hi[0][0] + off);
      bl[n] = *(const bf16x8*)(&Bs_lo[0][0] + off);
    }
#pragma unroll
    for (int m = 0; m < 8; ++m) {
      int r = wrl + m * 16 + fr;
      int off = r * 32 + ((q ^ ((r >> 1) & 3)) << 3);
      bf16x8 ah = *(const bf16x8*)(&As_hi[0][0] + off);
      bf16x8 al = *(const bf16x8*)(&As_lo[0][0] + off);
#pragma unroll
      for (int n = 0; n < 4; ++n) {
        acc[m][n] = __builtin_amdgcn_mfma_f32_16x16x32_bf16(ah, bh[n],
                                                            acc[m][n], 0, 0, 0);
        acc[m][n] = __builtin_amdgcn_mfma_f32_16x16x32_bf16(ah, bl[n],
                                                            acc[m][n], 0, 0, 0);
        acc[m][n] = __builtin_amdgcn_mfma_f32_16x16x32_bf16(al, bh[n],
                                                            acc[m][n], 0, 0, 0);
      }
    }
  }

  // epilogue: C/D layout col=lane&15, row=(lane>>4)*4+j  [m89/m91 verified]
  const int lcol = lane & 15;
  const int lrw = (lane >> 4) * 4;
#pragma unroll
  for (int m = 0; m < 8; ++m) {
    int gr0 = brow + wrl + m * 16 + lrw;
#pragma unroll
    for (int n = 0; n < 4; ++n) {
      int gc = bcol + wcl + n * 16 + lcol;
      float bv = bias[gc];
#pragma unroll
      for (int j = 0; j < 4; ++j) {
        int gr = gr0 + j;
        if (gr >= M) continue;
        float v = acc[m][n][j] + bv;
        if (RELU) v = fmaxf(v, 0.f);
        if (OUTBF) {
          short hv = f2bf(v);
          Chi[(size_t)gr * HIDC + gc] = hv;
          Clo[(size_t)gr * HIDC + gc] = f2bf(v - bf2f(hv));
        } else {
          Cf[(size_t)gr * HIDC + gc] = v;
        }
      }
    }
  }
}

extern "C" void kernel_launch(void* const* d_in, const int* in_sizes, int n_in,
                              void* d_out, int out_size, void* d_ws,
                              size_t ws_size, hipStream_t stream) {
  const float* x = (const float*)d_in[0];
  const int* ei = (const int*)d_in[1];
  const float* W1l = (const float*)d_in[2];
  const float* b1 = (const float*)d_in[3];
  const float* W1r = (const float*)d_in[4];
  const float* W2l = (const float*)d_in[5];
  const float* b2 = (const float*)d_in[6];
  const float* W2r = (const float*)d_in[7];
  float* out = (float*)d_out;

  const int N = in_sizes[0] / 128;  // 50000
  const int E = in_sizes[1] / 2;    // 800000
  const int* src = ei;
  const int* dst = ei + E;

  char* ws = (char*)d_ws;
  size_t off = 0;
  auto walloc = [&](size_t bytes) {
    void* p = ws + off;
    off += (bytes + 255) & ~(size_t)255;
    return p;
  };
  int* deg = (int*)walloc((size_t)N * 4);
  int* row_start = (int*)walloc((size_t)(N + 1) * 4);
  int* rank = (int*)walloc((size_t)E * 4);
  int* esrc = (int*)walloc((size_t)E * 4);
  int* bsum = (int*)walloc(256 * 4);
  int* boff = (int*)walloc(256 * 4);
  short* x_hi = (short*)walloc((size_t)N * 128 * 2);
  short* x_lo = (short*)walloc((size_t)N * 128 * 2);
  short* agg1_hi = (short*)walloc((size_t)N * 128 * 2);
  short* agg1_lo = (short*)walloc((size_t)N * 128 * 2);
  short* h_hi = (short*)walloc((size_t)N * 256 * 2);
  short* h_lo = (short*)walloc((size_t)N * 256 * 2);
  short* agg2_hi = (short*)walloc((size_t)N * 256 * 2);
  short* agg2_lo = (short*)walloc((size_t)N * 256 * 2);
  short* Wt1l_hi = (short*)walloc(128 * 256 * 2);
  short* Wt1l_lo = (short*)walloc(128 * 256 * 2);
  short* Wt1r_hi = (short*)walloc(128 * 256 * 2);
  short* Wt1r_lo = (short*)walloc(128 * 256 * 2);
  short* Wt2l_hi = (short*)walloc(256 * 256 * 2);
  short* Wt2l_lo = (short*)walloc(256 * 256 * 2);
  short* Wt2r_hi = (short*)walloc(256 * 256 * 2);
  short* Wt2r_lo = (short*)walloc(256 * 256 * 2);
  (void)ws_size;
  (void)n_in;
  (void)out_size;

  const int BLK = 256;
  const int eblocks = (E + BLK - 1) / BLK;
  const int nblocks = (N + BLK - 1) / BLK;  // 196

  // conversions (independent of CSR)
  xconv_kernel<<<(N * 32 + BLK - 1) / BLK, BLK, 0, stream>>>(
      (const float4*)x, (s16x4*)x_hi, (s16x4*)x_lo, N * 32);
  wconv_kernel<128, 256><<<(128 * 256 + BLK - 1) / BLK, BLK, 0, stream>>>(
      W1l, Wt1l_hi, Wt1l_lo);
  wconv_kernel<128, 256><<<(128 * 256 + BLK - 1) / BLK, BLK, 0, stream>>>(
      W1r, Wt1r_hi, Wt1r_lo);
  wconv_kernel<256, 256><<<(256 * 256 + BLK - 1) / BLK, BLK, 0, stream>>>(
      W2l, Wt2l_hi, Wt2l_lo);
  wconv_kernel<256, 256><<<(256 * 256 + BLK - 1) / BLK, BLK, 0, stream>>>(
      W2r, Wt2r_hi, Wt2r_lo);

  // CSR build: one atomic pass (rank) + parallel scan + non-atomic fill
  hipMemsetAsync(deg, 0, (size_t)N * 4, stream);
  deg_rank_kernel<<<eblocks, BLK, 0, stream>>>(dst, deg, rank, E, N);
  blocksum_kernel<<<nblocks, BLK, 0, stream>>>(deg, bsum, N);
  bscan_kernel<<<1, 256, 0, stream>>>(bsum, boff, row_start, nblocks, N);
  scatter_offsets_kernel<<<nblocks, BLK, 0, stream>>>(deg, boff, row_start, N);
  fill2_kernel<<<eblocks, BLK, 0, stream>>>(src, dst, rank, row_start, esrc, E,
                                            N);

  // layer 1
  gather1_kernel<<<(N * 16 + BLK - 1) / BLK, BLK, 0, stream>>>(
      x_hi, row_start, esrc, agg1_hi, agg1_lo, N);
  {
    mfma_gemm<128, true, true><<<400, BLK, 0, stream>>>(
        agg1_hi, agg1_lo, x_hi, x_lo, Wt1l_hi, Wt1l_lo, Wt1r_hi, Wt1r_lo, b1,
        nullptr, h_hi, h_lo, N);
  }

  // layer 2
  gather2_kernel<<<(N * 32 + BLK - 1) / BLK, BLK, 0, stream>>>(
      h_hi, row_start, esrc, agg2_hi, agg2_lo, N);
  {
    mfma_gemm<256, false, false><<<400, BLK, 0, stream>>>(
        agg2_hi, agg2_lo, h_hi, h_lo, Wt2l_hi, Wt2l_lo, Wt2r_hi, Wt2r_lo, b2,
        out, nullptr, nullptr, N);
  }
}